// Round 1
// baseline (1605.039 us; speedup 1.0000x reference)
//
#include <hip/hip_runtime.h>
#include <cstdint>
#include <cstddef>

#define L_SEQ 512
#define NBATCH 2
#define NTOK 1024          // B*L
#define E_DIM 1024
#define V_DIM 32000
#define DI_DIM 2048
#define NS_DIM 16
#define DTR_DIM 64
#define DC_DIM 4
#define NL_DIM 4

typedef __bf16 bf16;
typedef __bf16 bf16x8 __attribute__((ext_vector_type(8)));
typedef __bf16 bf16x4 __attribute__((ext_vector_type(4)));
typedef float  f32x4  __attribute__((ext_vector_type(4)));

// ---------------- cast f32 -> bf16 (grid-stride, x4) ----------------
__global__ void cast_f32_to_bf16(const float* __restrict__ in, bf16* __restrict__ out, int n4)
{
    int stride = gridDim.x * blockDim.x;
    for (int i = blockIdx.x * blockDim.x + threadIdx.x; i < n4; i += stride) {
        f32x4 v = ((const f32x4*)in)[i];
        bf16x4 o;
        o[0] = (bf16)v[0]; o[1] = (bf16)v[1]; o[2] = (bf16)v[2]; o[3] = (bf16)v[3];
        ((bf16x4*)out)[i] = o;
    }
}

// ---------------- embedding gather ----------------
__global__ void embed_kernel(const int* __restrict__ ids, const float* __restrict__ emb,
                             float* __restrict__ x)
{
    int t = blockIdx.x;
    int id = ids[t];
    ((f32x4*)(x + (size_t)t * E_DIM))[threadIdx.x] =
        ((const f32x4*)(emb + (size_t)id * E_DIM))[threadIdx.x];
}

// ---------------- LayerNorm (row=1024), bf16 out ----------------
__global__ void ln_kernel(const float* __restrict__ x, const float* __restrict__ w,
                          const float* __restrict__ b, bf16* __restrict__ out)
{
    int t = blockIdx.x;
    int tid = threadIdx.x;
    f32x4 v = ((const f32x4*)(x + (size_t)t * E_DIM))[tid];
    float s  = v[0] + v[1] + v[2] + v[3];
    float sq = v[0]*v[0] + v[1]*v[1] + v[2]*v[2] + v[3]*v[3];
#pragma unroll
    for (int off = 1; off < 64; off <<= 1) { s += __shfl_xor(s, off); sq += __shfl_xor(sq, off); }
    __shared__ float ps[4], pq[4];
    if ((tid & 63) == 0) { ps[tid >> 6] = s; pq[tid >> 6] = sq; }
    __syncthreads();
    float S  = ps[0] + ps[1] + ps[2] + ps[3];
    float SQ = pq[0] + pq[1] + pq[2] + pq[3];
    float mu  = S * (1.0f / E_DIM);
    float var = SQ * (1.0f / E_DIM) - mu * mu;
    float rs  = rsqrtf(var + 1e-5f);
    f32x4 wv = ((const f32x4*)w)[tid];
    f32x4 bv = ((const f32x4*)b)[tid];
    bf16x4 o;
#pragma unroll
    for (int i = 0; i < 4; ++i) o[i] = (bf16)((v[i] - mu) * rs * wv[i] + bv[i]);
    ((bf16x4*)(out + (size_t)t * E_DIM))[tid] = o;
}

// ---------------- MFMA bf16 GEMM: C[M,N] = A[M,K] * B[N,K]^T ----------------
// 128x128 tile, BK=32, 256 threads (4 waves, 2x2), single-buffered LDS.
// MODE 0: store; MODE 1: C += (residual); MODE 2: C = softplus(acc + bias[col])
template<int MODE>
__global__ __launch_bounds__(256) void gemm_bt(const bf16* __restrict__ A, const bf16* __restrict__ B,
                                               float* __restrict__ C, int M, int N, int K,
                                               int lda, int ldb, int ldc,
                                               const float* __restrict__ bias)
{
    __shared__ __align__(16) bf16 As[128 * 32];
    __shared__ __align__(16) bf16 Bs[128 * 32];
    int tid  = threadIdx.x;
    int lane = tid & 63;
    int wid  = tid >> 6;
    int wr = wid >> 1, wc = wid & 1;
    int li = lane & 15, lg = lane >> 4;
    const bf16* Ablk = A + (size_t)(blockIdx.y * 128) * lda;
    const bf16* Bblk = B + (size_t)(blockIdx.x * 128) * ldb;
    f32x4 acc[4][4] = {};
    for (int k0 = 0; k0 < K; k0 += 32) {
        __syncthreads();
#pragma unroll
        for (int j = 0; j < 2; ++j) {
            int idx = j * 256 + tid;          // 0..511
            int row = idx >> 2, seg = idx & 3;
            *(bf16x8*)&As[idx * 8] = *(const bf16x8*)(Ablk + (size_t)row * lda + k0 + seg * 8);
            *(bf16x8*)&Bs[idx * 8] = *(const bf16x8*)(Bblk + (size_t)row * ldb + k0 + seg * 8);
        }
        __syncthreads();
        bf16x8 af[4], bfr[4];
#pragma unroll
        for (int m = 0; m < 4; ++m) af[m]  = *(const bf16x8*)&As[(wr * 64 + m * 16 + li) * 32 + lg * 8];
#pragma unroll
        for (int n = 0; n < 4; ++n) bfr[n] = *(const bf16x8*)&Bs[(wc * 64 + n * 16 + li) * 32 + lg * 8];
#pragma unroll
        for (int m = 0; m < 4; ++m)
#pragma unroll
            for (int n = 0; n < 4; ++n)
                acc[m][n] = __builtin_amdgcn_mfma_f32_16x16x32_bf16(af[m], bfr[n], acc[m][n], 0, 0, 0);
    }
    int row0 = blockIdx.y * 128 + wr * 64;
    int col0 = blockIdx.x * 128 + wc * 64;
#pragma unroll
    for (int m = 0; m < 4; ++m) {
#pragma unroll
        for (int n = 0; n < 4; ++n) {
            int r = row0 + m * 16 + lg * 4;
            int c = col0 + n * 16 + li;
            float* cp = C + (size_t)r * ldc + c;
#pragma unroll
            for (int q = 0; q < 4; ++q) {
                float v = acc[m][n][q];
                if (MODE == 1) v += cp[(size_t)q * ldc];
                if (MODE == 2) {
                    float z = v + bias[c];
                    v = fmaxf(z, 0.0f) + log1pf(expf(-fabsf(z)));
                }
                cp[(size_t)q * ldc] = v;
            }
        }
    }
}

// ---------------- causal depthwise conv (DC=4) + SiLU ----------------
__global__ void conv_silu_kernel(const float* __restrict__ xz, const float* __restrict__ cw,
                                 const float* __restrict__ cb, float* __restrict__ u)
{
    int gid = blockIdx.x * 256 + threadIdx.x;   // 0 .. NTOK*DI/4-1
    int t  = gid >> 9;                          // /(DI/4)
    int d4 = (gid & 511) << 2;
    int l  = t & (L_SEQ - 1);
    f32x4 acc;
    acc[0] = cb[d4]; acc[1] = cb[d4 + 1]; acc[2] = cb[d4 + 2]; acc[3] = cb[d4 + 3];
    f32x4 w0 = ((const f32x4*)cw)[d4 + 0];
    f32x4 w1 = ((const f32x4*)cw)[d4 + 1];
    f32x4 w2 = ((const f32x4*)cw)[d4 + 2];
    f32x4 w3 = ((const f32x4*)cw)[d4 + 3];
#pragma unroll
    for (int k = 0; k < 4; ++k) {
        if (l + k >= 3) {
            f32x4 uv = *(const f32x4*)(xz + (size_t)(t + k - 3) * (2 * DI_DIM) + d4);
            acc[0] += w0[k] * uv[0];
            acc[1] += w1[k] * uv[1];
            acc[2] += w2[k] * uv[2];
            acc[3] += w3[k] * uv[3];
        }
    }
    f32x4 o;
#pragma unroll
    for (int i = 0; i < 4; ++i) { float a = acc[i]; o[i] = a / (1.0f + __expf(-a)); }
    *(f32x4*)(u + (size_t)t * DI_DIM + d4) = o;
}

// ---------------- x_proj: xdbl[1024,96] = u[1024,2048] @ xw[96,2048]^T (f32) ----------------
// block: 8 tokens, 128 threads (f = tid, active f<96). Also emits dt (cols 0..63) as bf16.
__global__ void xproj_kernel(const float* __restrict__ u, const float* __restrict__ xw,
                             float* __restrict__ xdbl, bf16* __restrict__ dt_bf)
{
    int t0 = blockIdx.x * 8;
    int f  = threadIdx.x;
    __shared__ __align__(16) float su[8][256];
    float acc[8] = {0,0,0,0,0,0,0,0};
    for (int kc = 0; kc < DI_DIM; kc += 256) {
        __syncthreads();
#pragma unroll
        for (int j = 0; j < 4; ++j) {
            int idx = j * 128 + threadIdx.x;    // 0..511 float4 index
            int tt = idx >> 6;
            int c4 = (idx & 63) * 4;
            *(f32x4*)&su[tt][c4] = *(const f32x4*)&u[(size_t)(t0 + tt) * DI_DIM + kc + c4];
        }
        __syncthreads();
        if (f < 96) {
            for (int kk = 0; kk < 256; kk += 4) {
                f32x4 wv = *(const f32x4*)&xw[(size_t)f * DI_DIM + kc + kk];
#pragma unroll
                for (int tt = 0; tt < 8; ++tt) {
                    f32x4 uv = *(f32x4*)&su[tt][kk];
                    acc[tt] += wv[0]*uv[0] + wv[1]*uv[1] + wv[2]*uv[2] + wv[3]*uv[3];
                }
            }
        }
    }
    if (f < 96) {
#pragma unroll
        for (int tt = 0; tt < 8; ++tt) {
            xdbl[(size_t)(t0 + tt) * 96 + f] = acc[tt];
            if (f < 64) dt_bf[(size_t)(t0 + tt) * DTR_DIM + f] = (bf16)acc[tt];
        }
    }
}

// ---------------- selective scan, fused with D-skip and silu(res) gating ----------------
// block: 256 threads = 16 d x 16 n; grid: NBATCH * DI/16 = 256
__global__ void scan_kernel(const float* __restrict__ delta, const float* __restrict__ xdbl,
                            const float* __restrict__ u, const float* __restrict__ xz,
                            const float* __restrict__ A_log, const float* __restrict__ D_par,
                            bf16* __restrict__ y)
{
    int tid = threadIdx.x;
    int b  = blockIdx.x >> 7;
    int d0 = (blockIdx.x & 127) << 4;
    int n  = tid & 15, dl = tid >> 4;
    int d  = d0 + dl;
    float Ac = -expf(A_log[(size_t)d * NS_DIM + n]);
    float Dp = D_par[d];
    float h = 0.0f;
    __shared__ float s_dlt[32][16];
    __shared__ float s_u[32][16];
    __shared__ float s_res[32][16];
    __shared__ float s_B[32][16];
    __shared__ float s_C[32][16];
    __shared__ bf16  s_y[32][16];
    int tt0 = tid >> 4, cc = tid & 15;
    for (int t0 = 0; t0 < L_SEQ; t0 += 32) {
#pragma unroll
        for (int j = 0; j < 2; ++j) {
            int tt = j * 16 + tt0;
            size_t trow = (size_t)(b * L_SEQ + t0 + tt);
            s_dlt[tt][cc] = delta[trow * DI_DIM + d0 + cc];
            s_u[tt][cc]   = u[trow * DI_DIM + d0 + cc];
            s_res[tt][cc] = xz[trow * (2 * DI_DIM) + DI_DIM + d0 + cc];
            s_B[tt][cc]   = xdbl[trow * 96 + 64 + cc];
            s_C[tt][cc]   = xdbl[trow * 96 + 80 + cc];
        }
        __syncthreads();
#pragma unroll
        for (int t = 0; t < 32; ++t) {
            float dlt = s_dlt[t][dl];
            float uu  = s_u[t][dl];
            float dA  = __expf(dlt * Ac);
            float dBu = dlt * s_B[t][n] * uu;
            h = fmaf(dA, h, dBu);
            float yp = h * s_C[t][n];
            yp += __shfl_xor(yp, 1);
            yp += __shfl_xor(yp, 2);
            yp += __shfl_xor(yp, 4);
            yp += __shfl_xor(yp, 8);
            if (n == 0) {
                float res = s_res[t][dl];
                float yv  = fmaf(uu, Dp, yp) * (res / (1.0f + __expf(-res)));
                s_y[t][dl] = (bf16)yv;
            }
        }
        __syncthreads();
#pragma unroll
        for (int j = 0; j < 2; ++j) {
            int tt = j * 16 + tt0;
            size_t trow = (size_t)(b * L_SEQ + t0 + tt);
            y[trow * DI_DIM + d0 + cc] = s_y[tt][cc];
        }
        __syncthreads();
    }
}

// ---------------- per-token logsumexp + NLL ----------------
__global__ void lse_nll_kernel(const float* __restrict__ logits, const int* __restrict__ targets,
                               float* __restrict__ nll)
{
    int t = blockIdx.x, tid = threadIdx.x;
    const f32x4* row = (const f32x4*)(logits + (size_t)t * V_DIM);
    float mx = -1e30f;
    for (int i = tid; i < V_DIM / 4; i += 256) {
        f32x4 v = row[i];
        mx = fmaxf(mx, fmaxf(fmaxf(v[0], v[1]), fmaxf(v[2], v[3])));
    }
#pragma unroll
    for (int off = 1; off < 64; off <<= 1) mx = fmaxf(mx, __shfl_xor(mx, off));
    __shared__ float pm[4], psum[4];
    if ((tid & 63) == 0) pm[tid >> 6] = mx;
    __syncthreads();
    mx = fmaxf(fmaxf(pm[0], pm[1]), fmaxf(pm[2], pm[3]));
    float s = 0.0f;
    for (int i = tid; i < V_DIM / 4; i += 256) {
        f32x4 v = row[i];
        s += __expf(v[0] - mx) + __expf(v[1] - mx) + __expf(v[2] - mx) + __expf(v[3] - mx);
    }
#pragma unroll
    for (int off = 1; off < 64; off <<= 1) s += __shfl_xor(s, off);
    if ((tid & 63) == 0) psum[tid >> 6] = s;
    __syncthreads();
    if (tid == 0) {
        float S = psum[0] + psum[1] + psum[2] + psum[3];
        int tg = targets[t];
        float v = 0.0f;
        if (tg >= 0) v = (mx + logf(S)) - logits[(size_t)t * V_DIM + tg];
        nll[t] = v;
    }
}

__global__ void loss_reduce_kernel(const float* __restrict__ nll, float* __restrict__ out)
{
    int tid = threadIdx.x;
    float s = 0.0f;
    for (int i = tid; i < NTOK; i += 256) s += nll[i];
#pragma unroll
    for (int off = 1; off < 64; off <<= 1) s += __shfl_xor(s, off);
    __shared__ float p[4];
    if ((tid & 63) == 0) p[tid >> 6] = s;
    __syncthreads();
    if (tid == 0) out[0] = (p[0] + p[1] + p[2] + p[3]) * (1.0f / NTOK);
}

// ---------------- host launcher ----------------
extern "C" void kernel_launch(void* const* d_in, const int* in_sizes, int n_in,
                              void* d_out, int out_size, void* d_ws, size_t ws_size,
                              hipStream_t stream)
{
    const int*   ids   = (const int*)d_in[0];
    const int*   tgt   = (const int*)d_in[1];
    const float* emb   = (const float*)d_in[2];
    const float* ln_w  = (const float*)d_in[3];
    const float* ln_b  = (const float*)d_in[4];
    const float* inw   = (const float*)d_in[5];
    const float* convw = (const float*)d_in[6];
    const float* convb = (const float*)d_in[7];
    const float* xw    = (const float*)d_in[8];
    const float* dtw   = (const float*)d_in[9];
    const float* dtb   = (const float*)d_in[10];
    const float* alog  = (const float*)d_in[11];
    const float* dpar  = (const float*)d_in[12];
    const float* outw  = (const float*)d_in[13];
    const float* flnw  = (const float*)d_in[14];
    const float* flnb  = (const float*)d_in[15];
    float* logits = (float*)d_out;
    float* lossp  = logits + (size_t)NTOK * V_DIM;

    char* wsp = (char*)d_ws;
    size_t off = 0;
    auto alloc = [&](size_t bytes) -> void* {
        void* p = wsp + off;
        off += (bytes + 255) & ~(size_t)255;
        return p;
    };
    bf16*  emb_bf  = (bf16*)alloc((size_t)V_DIM * E_DIM * 2);           // 65.5 MB
    bf16*  winl    = (bf16*)alloc((size_t)2 * DI_DIM * E_DIM * 2);      // 8.4 MB (per-layer)
    bf16*  woutl   = (bf16*)alloc((size_t)E_DIM * DI_DIM * 2);          // 4.2 MB
    bf16*  wdtl    = (bf16*)alloc((size_t)DI_DIM * DTR_DIM * 2);        // 0.26 MB
    float* x       = (float*)alloc((size_t)NTOK * E_DIM * 4);
    bf16*  h_bf    = (bf16*)alloc((size_t)NTOK * E_DIM * 2);
    float* xzb     = (float*)alloc((size_t)NTOK * 2 * DI_DIM * 4);
    float* ub      = (float*)alloc((size_t)NTOK * DI_DIM * 4);
    float* xdbl    = (float*)alloc((size_t)NTOK * 96 * 4);
    bf16*  dt_bf   = (bf16*)alloc((size_t)NTOK * DTR_DIM * 2);
    float* deltab  = (float*)alloc((size_t)NTOK * DI_DIM * 4);
    bf16*  y_bf    = (bf16*)alloc((size_t)NTOK * DI_DIM * 2);
    bf16*  xf_bf   = (bf16*)alloc((size_t)NTOK * E_DIM * 2);
    float* nll     = (float*)alloc((size_t)NTOK * 4);
    if (off > ws_size) return;  // ws too small: bail (outputs stay poisoned -> visible failure)

    auto cast = [&](const float* in, bf16* out, size_t n) {
        int n4 = (int)(n / 4);
        int grid = (n4 + 255) / 256; if (grid > 4096) grid = 4096;
        cast_f32_to_bf16<<<grid, 256, 0, stream>>>(in, out, n4);
    };
    cast(emb, emb_bf, (size_t)V_DIM * E_DIM);
    embed_kernel<<<NTOK, 256, 0, stream>>>(ids, emb, x);

    for (int l = 0; l < NL_DIM; ++l) {
        cast(inw  + (size_t)l * 2 * DI_DIM * E_DIM, winl,  (size_t)2 * DI_DIM * E_DIM);
        cast(outw + (size_t)l * E_DIM * DI_DIM,     woutl, (size_t)E_DIM * DI_DIM);
        cast(dtw  + (size_t)l * DI_DIM * DTR_DIM,   wdtl,  (size_t)DI_DIM * DTR_DIM);

        ln_kernel<<<NTOK, 256, 0, stream>>>(x, ln_w + l * E_DIM, ln_b + l * E_DIM, h_bf);
        // xz[1024,4096] = h @ in_w^T
        gemm_bt<0><<<dim3(2 * DI_DIM / 128, NTOK / 128), 256, 0, stream>>>(
            h_bf, winl, xzb, NTOK, 2 * DI_DIM, E_DIM, E_DIM, E_DIM, 2 * DI_DIM, nullptr);
        conv_silu_kernel<<<(NTOK * DI_DIM / 4) / 256, 256, 0, stream>>>(
            xzb, convw + l * DI_DIM * DC_DIM, convb + l * DI_DIM, ub);
        xproj_kernel<<<NTOK / 8, 128, 0, stream>>>(ub, xw + (size_t)l * 96 * DI_DIM, xdbl, dt_bf);
        // delta[1024,2048] = softplus(dt @ dtw^T + dtb)
        gemm_bt<2><<<dim3(DI_DIM / 128, NTOK / 128), 256, 0, stream>>>(
            dt_bf, wdtl, deltab, NTOK, DI_DIM, DTR_DIM, DTR_DIM, DTR_DIM, DI_DIM, dtb + l * DI_DIM);
        scan_kernel<<<NBATCH * DI_DIM / 16, 256, 0, stream>>>(
            deltab, xdbl, ub, xzb, alog + (size_t)l * DI_DIM * NS_DIM, dpar + l * DI_DIM, y_bf);
        // x += y @ out_w^T
        gemm_bt<1><<<dim3(E_DIM / 128, NTOK / 128), 256, 0, stream>>>(
            y_bf, woutl, x, NTOK, E_DIM, DI_DIM, DI_DIM, DI_DIM, E_DIM, nullptr);
    }
    ln_kernel<<<NTOK, 256, 0, stream>>>(x, flnw, flnb, xf_bf);
    // logits = x_f @ emb^T
    gemm_bt<0><<<dim3(V_DIM / 128, NTOK / 128), 256, 0, stream>>>(
        xf_bf, emb_bf, logits, NTOK, V_DIM, E_DIM, E_DIM, E_DIM, V_DIM, nullptr);
    lse_nll_kernel<<<NTOK, 256, 0, stream>>>(logits, tgt, nll);
    loss_reduce_kernel<<<1, 256, 0, stream>>>(nll, lossp);
}

// Round 2
// 1307.324 us; speedup vs baseline: 1.2277x; 1.2277x over previous
//
#include <hip/hip_runtime.h>
#include <cstdint>
#include <cstddef>

#define L_SEQ 512
#define NBATCH 2
#define NTOK 1024          // B*L
#define E_DIM 1024
#define V_DIM 32000
#define DI_DIM 2048
#define NS_DIM 16
#define DTR_DIM 64
#define DC_DIM 4
#define NL_DIM 4
#define NC 8               // time chunks for parallel scan
#define LC (L_SEQ / NC)    // 64

typedef __bf16 bf16;
typedef __bf16 bf16x8 __attribute__((ext_vector_type(8)));
typedef __bf16 bf16x4 __attribute__((ext_vector_type(4)));
typedef float  f32x4  __attribute__((ext_vector_type(4)));

// ---------------- cast f32 -> bf16 (grid-stride, x4) ----------------
__global__ void cast_f32_to_bf16(const float* __restrict__ in, bf16* __restrict__ out, int n4)
{
    int stride = gridDim.x * blockDim.x;
    for (int i = blockIdx.x * blockDim.x + threadIdx.x; i < n4; i += stride) {
        f32x4 v = ((const f32x4*)in)[i];
        bf16x4 o;
        o[0] = (bf16)v[0]; o[1] = (bf16)v[1]; o[2] = (bf16)v[2]; o[3] = (bf16)v[3];
        ((bf16x4*)out)[i] = o;
    }
}

// ---------------- embedding gather ----------------
__global__ void embed_kernel(const int* __restrict__ ids, const float* __restrict__ emb,
                             float* __restrict__ x)
{
    int t = blockIdx.x;
    int id = ids[t];
    ((f32x4*)(x + (size_t)t * E_DIM))[threadIdx.x] =
        ((const f32x4*)(emb + (size_t)id * E_DIM))[threadIdx.x];
}

// ---------------- LayerNorm (row=1024), bf16 out ----------------
__global__ void ln_kernel(const float* __restrict__ x, const float* __restrict__ w,
                          const float* __restrict__ b, bf16* __restrict__ out)
{
    int t = blockIdx.x;
    int tid = threadIdx.x;
    f32x4 v = ((const f32x4*)(x + (size_t)t * E_DIM))[tid];
    float s  = v[0] + v[1] + v[2] + v[3];
    float sq = v[0]*v[0] + v[1]*v[1] + v[2]*v[2] + v[3]*v[3];
#pragma unroll
    for (int off = 1; off < 64; off <<= 1) { s += __shfl_xor(s, off); sq += __shfl_xor(sq, off); }
    __shared__ float ps[4], pq[4];
    if ((tid & 63) == 0) { ps[tid >> 6] = s; pq[tid >> 6] = sq; }
    __syncthreads();
    float S  = ps[0] + ps[1] + ps[2] + ps[3];
    float SQ = pq[0] + pq[1] + pq[2] + pq[3];
    float mu  = S * (1.0f / E_DIM);
    float var = SQ * (1.0f / E_DIM) - mu * mu;
    float rs  = rsqrtf(var + 1e-5f);
    f32x4 wv = ((const f32x4*)w)[tid];
    f32x4 bv = ((const f32x4*)b)[tid];
    bf16x4 o;
#pragma unroll
    for (int i = 0; i < 4; ++i) o[i] = (bf16)((v[i] - mu) * rs * wv[i] + bv[i]);
    ((bf16x4*)(out + (size_t)t * E_DIM))[tid] = o;
}

// ---------------- MFMA bf16 GEMM: C[M,N] = A[M,K] * B[N,K]^T ----------------
// 128x128 tile, BK=32, 256 threads (4 waves, 2x2), single-buffered LDS.
// MODE 0: store; MODE 1: C += (residual); MODE 2: C = softplus(acc + bias[col])
template<int MODE>
__global__ __launch_bounds__(256) void gemm_bt(const bf16* __restrict__ A, const bf16* __restrict__ B,
                                               float* __restrict__ C, int M, int N, int K,
                                               int lda, int ldb, int ldc,
                                               const float* __restrict__ bias)
{
    __shared__ __align__(16) bf16 As[128 * 32];
    __shared__ __align__(16) bf16 Bs[128 * 32];
    int tid  = threadIdx.x;
    int lane = tid & 63;
    int wid  = tid >> 6;
    int wr = wid >> 1, wc = wid & 1;
    int li = lane & 15, lg = lane >> 4;
    const bf16* Ablk = A + (size_t)(blockIdx.y * 128) * lda;
    const bf16* Bblk = B + (size_t)(blockIdx.x * 128) * ldb;
    f32x4 acc[4][4] = {};
    for (int k0 = 0; k0 < K; k0 += 32) {
        __syncthreads();
#pragma unroll
        for (int j = 0; j < 2; ++j) {
            int idx = j * 256 + tid;          // 0..511
            int row = idx >> 2, seg = idx & 3;
            *(bf16x8*)&As[idx * 8] = *(const bf16x8*)(Ablk + (size_t)row * lda + k0 + seg * 8);
            *(bf16x8*)&Bs[idx * 8] = *(const bf16x8*)(Bblk + (size_t)row * ldb + k0 + seg * 8);
        }
        __syncthreads();
        bf16x8 af[4], bfr[4];
#pragma unroll
        for (int m = 0; m < 4; ++m) af[m]  = *(const bf16x8*)&As[(wr * 64 + m * 16 + li) * 32 + lg * 8];
#pragma unroll
        for (int n = 0; n < 4; ++n) bfr[n] = *(const bf16x8*)&Bs[(wc * 64 + n * 16 + li) * 32 + lg * 8];
#pragma unroll
        for (int m = 0; m < 4; ++m)
#pragma unroll
            for (int n = 0; n < 4; ++n)
                acc[m][n] = __builtin_amdgcn_mfma_f32_16x16x32_bf16(af[m], bfr[n], acc[m][n], 0, 0, 0);
    }
    int row0 = blockIdx.y * 128 + wr * 64;
    int col0 = blockIdx.x * 128 + wc * 64;
#pragma unroll
    for (int m = 0; m < 4; ++m) {
#pragma unroll
        for (int n = 0; n < 4; ++n) {
            int r = row0 + m * 16 + lg * 4;
            int c = col0 + n * 16 + li;
            float* cp = C + (size_t)r * ldc + c;
#pragma unroll
            for (int q = 0; q < 4; ++q) {
                float v = acc[m][n][q];
                if (MODE == 1) v += cp[(size_t)q * ldc];
                if (MODE == 2) {
                    float z = v + bias[c];
                    v = fmaxf(z, 0.0f) + log1pf(expf(-fabsf(z)));
                }
                cp[(size_t)q * ldc] = v;
            }
        }
    }
}

// ---------------- causal depthwise conv (DC=4) + SiLU ----------------
__global__ void conv_silu_kernel(const float* __restrict__ xz, const float* __restrict__ cw,
                                 const float* __restrict__ cb, float* __restrict__ u)
{
    int gid = blockIdx.x * 256 + threadIdx.x;   // 0 .. NTOK*DI/4-1
    int t  = gid >> 9;                          // /(DI/4)
    int d4 = (gid & 511) << 2;
    int l  = t & (L_SEQ - 1);
    f32x4 acc;
    acc[0] = cb[d4]; acc[1] = cb[d4 + 1]; acc[2] = cb[d4 + 2]; acc[3] = cb[d4 + 3];
    f32x4 w0 = ((const f32x4*)cw)[d4 + 0];
    f32x4 w1 = ((const f32x4*)cw)[d4 + 1];
    f32x4 w2 = ((const f32x4*)cw)[d4 + 2];
    f32x4 w3 = ((const f32x4*)cw)[d4 + 3];
#pragma unroll
    for (int k = 0; k < 4; ++k) {
        if (l + k >= 3) {
            f32x4 uv = *(const f32x4*)(xz + (size_t)(t + k - 3) * (2 * DI_DIM) + d4);
            acc[0] += w0[k] * uv[0];
            acc[1] += w1[k] * uv[1];
            acc[2] += w2[k] * uv[2];
            acc[3] += w3[k] * uv[3];
        }
    }
    f32x4 o;
#pragma unroll
    for (int i = 0; i < 4; ++i) { float a = acc[i]; o[i] = a / (1.0f + __expf(-a)); }
    *(f32x4*)(u + (size_t)t * DI_DIM + d4) = o;
}

// ---------------- x_proj: xdbl[1024,96] = u[1024,2048] @ xw[96,2048]^T (f32) ----------------
__global__ void xproj_kernel(const float* __restrict__ u, const float* __restrict__ xw,
                             float* __restrict__ xdbl, bf16* __restrict__ dt_bf)
{
    int t0 = blockIdx.x * 8;
    int f  = threadIdx.x;
    __shared__ __align__(16) float su[8][256];
    float acc[8] = {0,0,0,0,0,0,0,0};
    for (int kc = 0; kc < DI_DIM; kc += 256) {
        __syncthreads();
#pragma unroll
        for (int j = 0; j < 4; ++j) {
            int idx = j * 128 + threadIdx.x;    // 0..511 float4 index
            int tt = idx >> 6;
            int c4 = (idx & 63) * 4;
            *(f32x4*)&su[tt][c4] = *(const f32x4*)&u[(size_t)(t0 + tt) * DI_DIM + kc + c4];
        }
        __syncthreads();
        if (f < 96) {
            for (int kk = 0; kk < 256; kk += 4) {
                f32x4 wv = *(const f32x4*)&xw[(size_t)f * DI_DIM + kc + kk];
#pragma unroll
                for (int tt = 0; tt < 8; ++tt) {
                    f32x4 uv = *(f32x4*)&su[tt][kk];
                    acc[tt] += wv[0]*uv[0] + wv[1]*uv[1] + wv[2]*uv[2] + wv[3]*uv[3];
                }
            }
        }
    }
    if (f < 96) {
#pragma unroll
        for (int tt = 0; tt < 8; ++tt) {
            xdbl[(size_t)(t0 + tt) * 96 + f] = acc[tt];
            if (f < 64) dt_bf[(size_t)(t0 + tt) * DTR_DIM + f] = (bf16)acc[tt];
        }
    }
}

// ---------------- chunked selective scan ----------------
// Phase A: per-chunk transition (P = prod dA, S = h_end with h_start=0).
// grid: B * (DI/16) * NC = 2048 blocks; block 256 = 16d x 16n.
__global__ __launch_bounds__(256) void scan_phase_a(
        const float* __restrict__ delta, const float* __restrict__ xdbl,
        const float* __restrict__ u, const float* __restrict__ A_log,
        float* __restrict__ Pbuf, float* __restrict__ Sbuf)
{
    int tid = threadIdx.x;
    int c   = blockIdx.x & (NC - 1);
    int dblk= (blockIdx.x >> 3) & 127;
    int b   = blockIdx.x >> 10;
    int d0  = dblk << 4;
    int n = tid & 15, dl = tid >> 4;
    int d = d0 + dl;
    float Ac = -expf(A_log[(size_t)d * NS_DIM + n]);
    float h = 0.0f, P = 1.0f;
    __shared__ float s_dlt[32][16], s_u[32][16], s_B[32][16];
    int tt0 = tid >> 4, cc = tid & 15;
    int tbase = b * L_SEQ + c * LC;
    for (int t0 = 0; t0 < LC; t0 += 32) {
        __syncthreads();
#pragma unroll
        for (int j = 0; j < 2; ++j) {
            int tt = j * 16 + tt0;
            size_t trow = (size_t)(tbase + t0 + tt);
            s_dlt[tt][cc] = delta[trow * DI_DIM + d0 + cc];
            s_u[tt][cc]   = u[trow * DI_DIM + d0 + cc];
            s_B[tt][cc]   = xdbl[trow * 96 + 64 + cc];
        }
        __syncthreads();
#pragma unroll
        for (int t = 0; t < 32; ++t) {
            float dlt = s_dlt[t][dl];
            float dA  = __expf(dlt * Ac);
            h = fmaf(dA, h, dlt * s_B[t][n] * s_u[t][dl]);
            P *= dA;
        }
    }
    size_t oi = (((size_t)(b * NC + c) * DI_DIM) + d) * NS_DIM + n;
    Pbuf[oi] = P;
    Sbuf[oi] = h;
}

// Combine: serial scan over NC chunk transitions -> h_start per chunk.
// grid: B*DI*NS/256 = 256 blocks.
__global__ void scan_combine(const float* __restrict__ Pbuf, const float* __restrict__ Sbuf,
                             float* __restrict__ Hstart)
{
    int i  = blockIdx.x * 256 + threadIdx.x;    // (b, d, n) flat
    int b  = i >> 15;                            // / (DI*NS)
    int dn = i & 32767;
    float h = 0.0f;
#pragma unroll
    for (int c = 0; c < NC; ++c) {
        size_t oi = ((size_t)(b * NC + c) * (DI_DIM * NS_DIM)) + dn;
        Hstart[oi] = h;
        h = fmaf(Pbuf[oi], h, Sbuf[oi]);
    }
}

// Phase C: replay chunk from h_start, produce y (D-skip + silu(res) gating), bf16.
__global__ __launch_bounds__(256) void scan_phase_c(
        const float* __restrict__ delta, const float* __restrict__ xdbl,
        const float* __restrict__ u, const float* __restrict__ xz,
        const float* __restrict__ A_log, const float* __restrict__ D_par,
        const float* __restrict__ Hstart, bf16* __restrict__ y)
{
    int tid = threadIdx.x;
    int c   = blockIdx.x & (NC - 1);
    int dblk= (blockIdx.x >> 3) & 127;
    int b   = blockIdx.x >> 10;
    int d0  = dblk << 4;
    int n = tid & 15, dl = tid >> 4;
    int d = d0 + dl;
    float Ac = -expf(A_log[(size_t)d * NS_DIM + n]);
    float Dp = D_par[d];
    float h = Hstart[(((size_t)(b * NC + c) * DI_DIM) + d) * NS_DIM + n];
    __shared__ float s_dlt[32][16], s_u[32][16], s_res[32][16], s_B[32][16], s_C[32][16];
    __shared__ bf16  s_y[32][16];
    int tt0 = tid >> 4, cc = tid & 15;
    int tbase = b * L_SEQ + c * LC;
    for (int t0 = 0; t0 < LC; t0 += 32) {
        __syncthreads();
#pragma unroll
        for (int j = 0; j < 2; ++j) {
            int tt = j * 16 + tt0;
            size_t trow = (size_t)(tbase + t0 + tt);
            s_dlt[tt][cc] = delta[trow * DI_DIM + d0 + cc];
            s_u[tt][cc]   = u[trow * DI_DIM + d0 + cc];
            s_res[tt][cc] = xz[trow * (2 * DI_DIM) + DI_DIM + d0 + cc];
            s_B[tt][cc]   = xdbl[trow * 96 + 64 + cc];
            s_C[tt][cc]   = xdbl[trow * 96 + 80 + cc];
        }
        __syncthreads();
#pragma unroll
        for (int t = 0; t < 32; ++t) {
            float dlt = s_dlt[t][dl];
            float uu  = s_u[t][dl];
            float dA  = __expf(dlt * Ac);
            float dBu = dlt * s_B[t][n] * uu;
            h = fmaf(dA, h, dBu);
            float yp = h * s_C[t][n];
            yp += __shfl_xor(yp, 1);
            yp += __shfl_xor(yp, 2);
            yp += __shfl_xor(yp, 4);
            yp += __shfl_xor(yp, 8);
            if (n == 0) {
                float res = s_res[t][dl];
                float yv  = fmaf(uu, Dp, yp) * (res / (1.0f + __expf(-res)));
                s_y[t][dl] = (bf16)yv;
            }
        }
        __syncthreads();
#pragma unroll
        for (int j = 0; j < 2; ++j) {
            int tt = j * 16 + tt0;
            size_t trow = (size_t)(tbase + t0 + tt);
            y[trow * DI_DIM + d0 + cc] = s_y[tt][cc];
        }
    }
}

// ---------------- per-token logsumexp + NLL ----------------
__global__ void lse_nll_kernel(const float* __restrict__ logits, const int* __restrict__ targets,
                               float* __restrict__ nll)
{
    int t = blockIdx.x, tid = threadIdx.x;
    const f32x4* row = (const f32x4*)(logits + (size_t)t * V_DIM);
    float mx = -1e30f;
    for (int i = tid; i < V_DIM / 4; i += 256) {
        f32x4 v = row[i];
        mx = fmaxf(mx, fmaxf(fmaxf(v[0], v[1]), fmaxf(v[2], v[3])));
    }
#pragma unroll
    for (int off = 1; off < 64; off <<= 1) mx = fmaxf(mx, __shfl_xor(mx, off));
    __shared__ float pm[4], psum[4];
    if ((tid & 63) == 0) pm[tid >> 6] = mx;
    __syncthreads();
    mx = fmaxf(fmaxf(pm[0], pm[1]), fmaxf(pm[2], pm[3]));
    float s = 0.0f;
    for (int i = tid; i < V_DIM / 4; i += 256) {
        f32x4 v = row[i];
        s += __expf(v[0] - mx) + __expf(v[1] - mx) + __expf(v[2] - mx) + __expf(v[3] - mx);
    }
#pragma unroll
    for (int off = 1; off < 64; off <<= 1) s += __shfl_xor(s, off);
    if ((tid & 63) == 0) psum[tid >> 6] = s;
    __syncthreads();
    if (tid == 0) {
        float S = psum[0] + psum[1] + psum[2] + psum[3];
        int tg = targets[t];
        float v = 0.0f;
        if (tg >= 0) v = (mx + logf(S)) - logits[(size_t)t * V_DIM + tg];
        nll[t] = v;
    }
}

__global__ void loss_reduce_kernel(const float* __restrict__ nll, float* __restrict__ out)
{
    int tid = threadIdx.x;
    float s = 0.0f;
    for (int i = tid; i < NTOK; i += 256) s += nll[i];
#pragma unroll
    for (int off = 1; off < 64; off <<= 1) s += __shfl_xor(s, off);
    __shared__ float p[4];
    if ((tid & 63) == 0) p[tid >> 6] = s;
    __syncthreads();
    if (tid == 0) out[0] = (p[0] + p[1] + p[2] + p[3]) * (1.0f / NTOK);
}

// ---------------- host launcher ----------------
extern "C" void kernel_launch(void* const* d_in, const int* in_sizes, int n_in,
                              void* d_out, int out_size, void* d_ws, size_t ws_size,
                              hipStream_t stream)
{
    const int*   ids   = (const int*)d_in[0];
    const int*   tgt   = (const int*)d_in[1];
    const float* emb   = (const float*)d_in[2];
    const float* ln_w  = (const float*)d_in[3];
    const float* ln_b  = (const float*)d_in[4];
    const float* inw   = (const float*)d_in[5];
    const float* convw = (const float*)d_in[6];
    const float* convb = (const float*)d_in[7];
    const float* xw    = (const float*)d_in[8];
    const float* dtw   = (const float*)d_in[9];
    const float* dtb   = (const float*)d_in[10];
    const float* alog  = (const float*)d_in[11];
    const float* dpar  = (const float*)d_in[12];
    const float* outw  = (const float*)d_in[13];
    const float* flnw  = (const float*)d_in[14];
    const float* flnb  = (const float*)d_in[15];
    float* logits = (float*)d_out;
    float* lossp  = logits + (size_t)NTOK * V_DIM;

    char* wsp = (char*)d_ws;
    size_t off = 0;
    auto alloc = [&](size_t bytes) -> void* {
        void* p = wsp + off;
        off += (bytes + 255) & ~(size_t)255;
        return p;
    };
    bf16*  emb_bf  = (bf16*)alloc((size_t)V_DIM * E_DIM * 2);           // 65.5 MB
    bf16*  winl    = (bf16*)alloc((size_t)2 * DI_DIM * E_DIM * 2);      // 8.4 MB (per-layer)
    bf16*  woutl   = (bf16*)alloc((size_t)E_DIM * DI_DIM * 2);          // 4.2 MB
    bf16*  wdtl    = (bf16*)alloc((size_t)DI_DIM * DTR_DIM * 2);        // 0.26 MB
    float* x       = (float*)alloc((size_t)NTOK * E_DIM * 4);
    bf16*  h_bf    = (bf16*)alloc((size_t)NTOK * E_DIM * 2);
    float* xzb     = (float*)alloc((size_t)NTOK * 2 * DI_DIM * 4);
    float* ub      = (float*)alloc((size_t)NTOK * DI_DIM * 4);
    float* xdbl    = (float*)alloc((size_t)NTOK * 96 * 4);
    bf16*  dt_bf   = (bf16*)alloc((size_t)NTOK * DTR_DIM * 2);
    float* deltab  = (float*)alloc((size_t)NTOK * DI_DIM * 4);
    bf16*  y_bf    = (bf16*)alloc((size_t)NTOK * DI_DIM * 2);
    bf16*  xf_bf   = (bf16*)alloc((size_t)NTOK * E_DIM * 2);
    float* nll     = (float*)alloc((size_t)NTOK * 4);
    float* Pbuf    = (float*)alloc((size_t)NBATCH * NC * DI_DIM * NS_DIM * 4);  // 2 MB
    float* Sbuf    = (float*)alloc((size_t)NBATCH * NC * DI_DIM * NS_DIM * 4);  // 2 MB
    float* Hstart  = (float*)alloc((size_t)NBATCH * NC * DI_DIM * NS_DIM * 4);  // 2 MB
    if (off > ws_size) return;  // ws too small: bail (outputs stay poisoned -> visible failure)

    auto cast = [&](const float* in, bf16* out, size_t n) {
        int n4 = (int)(n / 4);
        int grid = (n4 + 255) / 256; if (grid > 4096) grid = 4096;
        cast_f32_to_bf16<<<grid, 256, 0, stream>>>(in, out, n4);
    };
    cast(emb, emb_bf, (size_t)V_DIM * E_DIM);
    embed_kernel<<<NTOK, 256, 0, stream>>>(ids, emb, x);

    for (int l = 0; l < NL_DIM; ++l) {
        cast(inw  + (size_t)l * 2 * DI_DIM * E_DIM, winl,  (size_t)2 * DI_DIM * E_DIM);
        cast(outw + (size_t)l * E_DIM * DI_DIM,     woutl, (size_t)E_DIM * DI_DIM);
        cast(dtw  + (size_t)l * DI_DIM * DTR_DIM,   wdtl,  (size_t)DI_DIM * DTR_DIM);

        ln_kernel<<<NTOK, 256, 0, stream>>>(x, ln_w + l * E_DIM, ln_b + l * E_DIM, h_bf);
        // xz[1024,4096] = h @ in_w^T
        gemm_bt<0><<<dim3(2 * DI_DIM / 128, NTOK / 128), 256, 0, stream>>>(
            h_bf, winl, xzb, NTOK, 2 * DI_DIM, E_DIM, E_DIM, E_DIM, 2 * DI_DIM, nullptr);
        conv_silu_kernel<<<(NTOK * DI_DIM / 4) / 256, 256, 0, stream>>>(
            xzb, convw + l * DI_DIM * DC_DIM, convb + l * DI_DIM, ub);
        xproj_kernel<<<NTOK / 8, 128, 0, stream>>>(ub, xw + (size_t)l * 96 * DI_DIM, xdbl, dt_bf);
        // delta[1024,2048] = softplus(dt @ dtw^T + dtb)
        gemm_bt<2><<<dim3(DI_DIM / 128, NTOK / 128), 256, 0, stream>>>(
            dt_bf, wdtl, deltab, NTOK, DI_DIM, DTR_DIM, DTR_DIM, DTR_DIM, DI_DIM, dtb + l * DI_DIM);
        // chunked scan
        scan_phase_a<<<NBATCH * (DI_DIM / 16) * NC, 256, 0, stream>>>(
            deltab, xdbl, ub, alog + (size_t)l * DI_DIM * NS_DIM, Pbuf, Sbuf);
        scan_combine<<<NBATCH * DI_DIM * NS_DIM / 256, 256, 0, stream>>>(Pbuf, Sbuf, Hstart);
        scan_phase_c<<<NBATCH * (DI_DIM / 16) * NC, 256, 0, stream>>>(
            deltab, xdbl, ub, xzb, alog + (size_t)l * DI_DIM * NS_DIM, dpar + l * DI_DIM,
            Hstart, y_bf);
        // x += y @ out_w^T
        gemm_bt<1><<<dim3(E_DIM / 128, NTOK / 128), 256, 0, stream>>>(
            y_bf, woutl, x, NTOK, E_DIM, DI_DIM, DI_DIM, DI_DIM, E_DIM, nullptr);
    }
    ln_kernel<<<NTOK, 256, 0, stream>>>(x, flnw, flnb, xf_bf);
    // logits = x_f @ emb^T
    gemm_bt<0><<<dim3(V_DIM / 128, NTOK / 128), 256, 0, stream>>>(
        xf_bf, emb_bf, logits, NTOK, V_DIM, E_DIM, E_DIM, E_DIM, V_DIM, nullptr);
    lse_nll_kernel<<<NTOK, 256, 0, stream>>>(logits, tgt, nll);
    loss_reduce_kernel<<<1, 256, 0, stream>>>(nll, lossp);
}

// Round 3
// 1284.260 us; speedup vs baseline: 1.2498x; 1.0180x over previous
//
#include <hip/hip_runtime.h>
#include <cstdint>
#include <cstddef>

#define L_SEQ 512
#define NBATCH 2
#define NTOK 1024          // B*L
#define E_DIM 1024
#define V_DIM 32000
#define DI_DIM 2048
#define NS_DIM 16
#define DTR_DIM 64
#define DC_DIM 4
#define NL_DIM 4
#define NC 8               // time chunks for parallel scan
#define LC (L_SEQ / NC)    // 64

typedef __bf16 bf16;
typedef __bf16 bf16x8 __attribute__((ext_vector_type(8)));
typedef __bf16 bf16x4 __attribute__((ext_vector_type(4)));
typedef float  f32x4  __attribute__((ext_vector_type(4)));

// async global->LDS, 16B per lane. LDS dest is wave-uniform base + lane*16.
__device__ __forceinline__ void gload_lds16(const void* g, void* l)
{
    __builtin_amdgcn_global_load_lds((const __attribute__((address_space(1))) uint32_t*)g,
                                     (__attribute__((address_space(3))) uint32_t*)l, 16, 0, 0);
}

// ---------------- cast f32 -> bf16 (grid-stride, x4) ----------------
__global__ void cast_f32_to_bf16(const float* __restrict__ in, bf16* __restrict__ out, int n4)
{
    int stride = gridDim.x * blockDim.x;
    for (int i = blockIdx.x * blockDim.x + threadIdx.x; i < n4; i += stride) {
        f32x4 v = ((const f32x4*)in)[i];
        bf16x4 o;
        o[0] = (bf16)v[0]; o[1] = (bf16)v[1]; o[2] = (bf16)v[2]; o[3] = (bf16)v[3];
        ((bf16x4*)out)[i] = o;
    }
}

// ---------------- embedding gather ----------------
__global__ void embed_kernel(const int* __restrict__ ids, const float* __restrict__ emb,
                             float* __restrict__ x)
{
    int t = blockIdx.x;
    int id = ids[t];
    ((f32x4*)(x + (size_t)t * E_DIM))[threadIdx.x] =
        ((const f32x4*)(emb + (size_t)id * E_DIM))[threadIdx.x];
}

// ---------------- LayerNorm (row=1024), bf16 out ----------------
__global__ void ln_kernel(const float* __restrict__ x, const float* __restrict__ w,
                          const float* __restrict__ b, bf16* __restrict__ out)
{
    int t = blockIdx.x;
    int tid = threadIdx.x;
    f32x4 v = ((const f32x4*)(x + (size_t)t * E_DIM))[tid];
    float s  = v[0] + v[1] + v[2] + v[3];
    float sq = v[0]*v[0] + v[1]*v[1] + v[2]*v[2] + v[3]*v[3];
#pragma unroll
    for (int off = 1; off < 64; off <<= 1) { s += __shfl_xor(s, off); sq += __shfl_xor(sq, off); }
    __shared__ float ps[4], pq[4];
    if ((tid & 63) == 0) { ps[tid >> 6] = s; pq[tid >> 6] = sq; }
    __syncthreads();
    float S  = ps[0] + ps[1] + ps[2] + ps[3];
    float SQ = pq[0] + pq[1] + pq[2] + pq[3];
    float mu  = S * (1.0f / E_DIM);
    float var = SQ * (1.0f / E_DIM) - mu * mu;
    float rs  = rsqrtf(var + 1e-5f);
    f32x4 wv = ((const f32x4*)w)[tid];
    f32x4 bv = ((const f32x4*)b)[tid];
    bf16x4 o;
#pragma unroll
    for (int i = 0; i < 4; ++i) o[i] = (bf16)((v[i] - mu) * rs * wv[i] + bv[i]);
    ((bf16x4*)(out + (size_t)t * E_DIM))[tid] = o;
}

// ---------------- MFMA bf16 GEMM: C[M,N] = A[M,K] * B[N,K]^T ----------------
// 128x128 tile, BK=32, 256 threads (4 waves, 2x2). global_load_lds staging.
// Grid: x = row-block (M/128), y = col-block (N/128) -> rows-fastest dispatch
// so all row-blocks sharing one B-tile run in the same dispatch window (L3 reuse).
// MODE 0: store; MODE 1: C += (residual); MODE 2: C = softplus(acc + bias[col])
template<int MODE>
__global__ __launch_bounds__(256) void gemm_bt(const bf16* __restrict__ A, const bf16* __restrict__ B,
                                               float* __restrict__ C, int M, int N, int K,
                                               int lda, int ldb, int ldc,
                                               const float* __restrict__ bias)
{
    __shared__ __align__(16) bf16 As[128 * 32];
    __shared__ __align__(16) bf16 Bs[128 * 32];
    int tid  = threadIdx.x;
    int lane = tid & 63;
    int wid  = tid >> 6;
    int wr = wid >> 1, wc = wid & 1;
    int li = lane & 15, lg = lane >> 4;
    int rb = blockIdx.x, cb = blockIdx.y;
    const bf16* Ablk = A + (size_t)(rb * 128) * lda;
    const bf16* Bblk = B + (size_t)(cb * 128) * ldb;
    // staging address pieces: idx = j*256 + tid covers 512 lane-ops of 16B = 8KB
    int srow = (wid * 64 + lane) >> 2;      // row within 128 for j=0 (adds 64 for j=1)
    int sseg = (lane & 3) * 8;              // 8-bf16 segment within the 32-wide K slab
    f32x4 acc[4][4] = {};
    for (int k0 = 0; k0 < K; k0 += 32) {
        __syncthreads();
#pragma unroll
        for (int j = 0; j < 2; ++j) {
            int row = srow + j * 64;
            const bf16* ga = Ablk + (size_t)row * lda + k0 + sseg;
            const bf16* gb = Bblk + (size_t)row * ldb + k0 + sseg;
            bf16* la = As + ((size_t)j * 256 + wid * 64) * 8;
            bf16* lb = Bs + ((size_t)j * 256 + wid * 64) * 8;
            gload_lds16(ga, la);
            gload_lds16(gb, lb);
        }
        __syncthreads();   // compiler emits s_waitcnt vmcnt(0) before s_barrier
        bf16x8 af[4], bfr[4];
#pragma unroll
        for (int m = 0; m < 4; ++m) af[m]  = *(const bf16x8*)&As[(wr * 64 + m * 16 + li) * 32 + lg * 8];
#pragma unroll
        for (int n = 0; n < 4; ++n) bfr[n] = *(const bf16x8*)&Bs[(wc * 64 + n * 16 + li) * 32 + lg * 8];
#pragma unroll
        for (int m = 0; m < 4; ++m)
#pragma unroll
            for (int n = 0; n < 4; ++n)
                acc[m][n] = __builtin_amdgcn_mfma_f32_16x16x32_bf16(af[m], bfr[n], acc[m][n], 0, 0, 0);
    }
    int row0 = rb * 128 + wr * 64;
    int col0 = cb * 128 + wc * 64;
#pragma unroll
    for (int m = 0; m < 4; ++m) {
#pragma unroll
        for (int n = 0; n < 4; ++n) {
            int r = row0 + m * 16 + lg * 4;
            int c = col0 + n * 16 + li;
            float* cp = C + (size_t)r * ldc + c;
#pragma unroll
            for (int q = 0; q < 4; ++q) {
                float v = acc[m][n][q];
                if (MODE == 1) v += cp[(size_t)q * ldc];
                if (MODE == 2) {
                    float z = v + bias[c];
                    v = fmaxf(z, 0.0f) + log1pf(expf(-fabsf(z)));
                }
                cp[(size_t)q * ldc] = v;
            }
        }
    }
}

// ---------------- causal depthwise conv (DC=4) + SiLU ----------------
__global__ void conv_silu_kernel(const float* __restrict__ xz, const float* __restrict__ cw,
                                 const float* __restrict__ cb, float* __restrict__ u)
{
    int gid = blockIdx.x * 256 + threadIdx.x;   // 0 .. NTOK*DI/4-1
    int t  = gid >> 9;                          // /(DI/4)
    int d4 = (gid & 511) << 2;
    int l  = t & (L_SEQ - 1);
    f32x4 acc;
    acc[0] = cb[d4]; acc[1] = cb[d4 + 1]; acc[2] = cb[d4 + 2]; acc[3] = cb[d4 + 3];
    f32x4 w0 = ((const f32x4*)cw)[d4 + 0];
    f32x4 w1 = ((const f32x4*)cw)[d4 + 1];
    f32x4 w2 = ((const f32x4*)cw)[d4 + 2];
    f32x4 w3 = ((const f32x4*)cw)[d4 + 3];
#pragma unroll
    for (int k = 0; k < 4; ++k) {
        if (l + k >= 3) {
            f32x4 uv = *(const f32x4*)(xz + (size_t)(t + k - 3) * (2 * DI_DIM) + d4);
            acc[0] += w0[k] * uv[0];
            acc[1] += w1[k] * uv[1];
            acc[2] += w2[k] * uv[2];
            acc[3] += w3[k] * uv[3];
        }
    }
    f32x4 o;
#pragma unroll
    for (int i = 0; i < 4; ++i) { float a = acc[i]; o[i] = a / (1.0f + __expf(-a)); }
    *(f32x4*)(u + (size_t)t * DI_DIM + d4) = o;
}

// ---------------- x_proj: xdbl[1024,96] = u[1024,2048] @ xw[96,2048]^T (f32) ----------------
__global__ void xproj_kernel(const float* __restrict__ u, const float* __restrict__ xw,
                             float* __restrict__ xdbl, bf16* __restrict__ dt_bf)
{
    int t0 = blockIdx.x * 8;
    int f  = threadIdx.x;
    __shared__ __align__(16) float su[8][256];
    float acc[8] = {0,0,0,0,0,0,0,0};
    for (int kc = 0; kc < DI_DIM; kc += 256) {
        __syncthreads();
#pragma unroll
        for (int j = 0; j < 4; ++j) {
            int idx = j * 128 + threadIdx.x;    // 0..511 float4 index
            int tt = idx >> 6;
            int c4 = (idx & 63) * 4;
            *(f32x4*)&su[tt][c4] = *(const f32x4*)&u[(size_t)(t0 + tt) * DI_DIM + kc + c4];
        }
        __syncthreads();
        if (f < 96) {
            for (int kk = 0; kk < 256; kk += 4) {
                f32x4 wv = *(const f32x4*)&xw[(size_t)f * DI_DIM + kc + kk];
#pragma unroll
                for (int tt = 0; tt < 8; ++tt) {
                    f32x4 uv = *(f32x4*)&su[tt][kk];
                    acc[tt] += wv[0]*uv[0] + wv[1]*uv[1] + wv[2]*uv[2] + wv[3]*uv[3];
                }
            }
        }
    }
    if (f < 96) {
#pragma unroll
        for (int tt = 0; tt < 8; ++tt) {
            xdbl[(size_t)(t0 + tt) * 96 + f] = acc[tt];
            if (f < 64) dt_bf[(size_t)(t0 + tt) * DTR_DIM + f] = (bf16)acc[tt];
        }
    }
}

// ---------------- chunked selective scan ----------------
__global__ __launch_bounds__(256) void scan_phase_a(
        const float* __restrict__ delta, const float* __restrict__ xdbl,
        const float* __restrict__ u, const float* __restrict__ A_log,
        float* __restrict__ Pbuf, float* __restrict__ Sbuf)
{
    int tid = threadIdx.x;
    int c   = blockIdx.x & (NC - 1);
    int dblk= (blockIdx.x >> 3) & 127;
    int b   = blockIdx.x >> 10;
    int d0  = dblk << 4;
    int n = tid & 15, dl = tid >> 4;
    int d = d0 + dl;
    float Ac = -expf(A_log[(size_t)d * NS_DIM + n]);
    float h = 0.0f, P = 1.0f;
    __shared__ float s_dlt[32][16], s_u[32][16], s_B[32][16];
    int tt0 = tid >> 4, cc = tid & 15;
    int tbase = b * L_SEQ + c * LC;
    for (int t0 = 0; t0 < LC; t0 += 32) {
        __syncthreads();
#pragma unroll
        for (int j = 0; j < 2; ++j) {
            int tt = j * 16 + tt0;
            size_t trow = (size_t)(tbase + t0 + tt);
            s_dlt[tt][cc] = delta[trow * DI_DIM + d0 + cc];
            s_u[tt][cc]   = u[trow * DI_DIM + d0 + cc];
            s_B[tt][cc]   = xdbl[trow * 96 + 64 + cc];
        }
        __syncthreads();
#pragma unroll
        for (int t = 0; t < 32; ++t) {
            float dlt = s_dlt[t][dl];
            float dA  = __expf(dlt * Ac);
            h = fmaf(dA, h, dlt * s_B[t][n] * s_u[t][dl]);
            P *= dA;
        }
    }
    size_t oi = (((size_t)(b * NC + c) * DI_DIM) + d) * NS_DIM + n;
    Pbuf[oi] = P;
    Sbuf[oi] = h;
}

__global__ void scan_combine(const float* __restrict__ Pbuf, const float* __restrict__ Sbuf,
                             float* __restrict__ Hstart)
{
    int i  = blockIdx.x * 256 + threadIdx.x;    // (b, d, n) flat
    int b  = i >> 15;                            // / (DI*NS)
    int dn = i & 32767;
    float h = 0.0f;
#pragma unroll
    for (int c = 0; c < NC; ++c) {
        size_t oi = ((size_t)(b * NC + c) * (DI_DIM * NS_DIM)) + dn;
        Hstart[oi] = h;
        h = fmaf(Pbuf[oi], h, Sbuf[oi]);
    }
}

__global__ __launch_bounds__(256) void scan_phase_c(
        const float* __restrict__ delta, const float* __restrict__ xdbl,
        const float* __restrict__ u, const float* __restrict__ xz,
        const float* __restrict__ A_log, const float* __restrict__ D_par,
        const float* __restrict__ Hstart, bf16* __restrict__ y)
{
    int tid = threadIdx.x;
    int c   = blockIdx.x & (NC - 1);
    int dblk= (blockIdx.x >> 3) & 127;
    int b   = blockIdx.x >> 10;
    int d0  = dblk << 4;
    int n = tid & 15, dl = tid >> 4;
    int d = d0 + dl;
    float Ac = -expf(A_log[(size_t)d * NS_DIM + n]);
    float Dp = D_par[d];
    float h = Hstart[(((size_t)(b * NC + c) * DI_DIM) + d) * NS_DIM + n];
    __shared__ float s_dlt[32][16], s_u[32][16], s_res[32][16], s_B[32][16], s_C[32][16];
    __shared__ bf16  s_y[32][16];
    int tt0 = tid >> 4, cc = tid & 15;
    int tbase = b * L_SEQ + c * LC;
    for (int t0 = 0; t0 < LC; t0 += 32) {
        __syncthreads();
#pragma unroll
        for (int j = 0; j < 2; ++j) {
            int tt = j * 16 + tt0;
            size_t trow = (size_t)(tbase + t0 + tt);
            s_dlt[tt][cc] = delta[trow * DI_DIM + d0 + cc];
            s_u[tt][cc]   = u[trow * DI_DIM + d0 + cc];
            s_res[tt][cc] = xz[trow * (2 * DI_DIM) + DI_DIM + d0 + cc];
            s_B[tt][cc]   = xdbl[trow * 96 + 64 + cc];
            s_C[tt][cc]   = xdbl[trow * 96 + 80 + cc];
        }
        __syncthreads();
#pragma unroll
        for (int t = 0; t < 32; ++t) {
            float dlt = s_dlt[t][dl];
            float uu  = s_u[t][dl];
            float dA  = __expf(dlt * Ac);
            float dBu = dlt * s_B[t][n] * uu;
            h = fmaf(dA, h, dBu);
            float yp = h * s_C[t][n];
            yp += __shfl_xor(yp, 1);
            yp += __shfl_xor(yp, 2);
            yp += __shfl_xor(yp, 4);
            yp += __shfl_xor(yp, 8);
            if (n == 0) {
                float res = s_res[t][dl];
                float yv  = fmaf(uu, Dp, yp) * (res / (1.0f + __expf(-res)));
                s_y[t][dl] = (bf16)yv;
            }
        }
        __syncthreads();
#pragma unroll
        for (int j = 0; j < 2; ++j) {
            int tt = j * 16 + tt0;
            size_t trow = (size_t)(tbase + t0 + tt);
            y[trow * DI_DIM + d0 + cc] = s_y[tt][cc];
        }
    }
}

// ---------------- per-token online logsumexp + NLL (single pass) ----------------
__global__ void lse_nll_kernel(const float* __restrict__ logits, const int* __restrict__ targets,
                               float* __restrict__ nll)
{
    int t = blockIdx.x, tid = threadIdx.x;
    const f32x4* row = (const f32x4*)(logits + (size_t)t * V_DIM);
    float m = -1e30f, s = 0.0f;
    for (int i = tid; i < V_DIM / 4; i += 256) {
        f32x4 v = row[i];
        float m4 = fmaxf(fmaxf(v[0], v[1]), fmaxf(v[2], v[3]));
        if (m4 > m) { s *= __expf(m - m4); m = m4; }   // defer-max: rescale only on growth
        s += __expf(v[0] - m) + __expf(v[1] - m) + __expf(v[2] - m) + __expf(v[3] - m);
    }
#pragma unroll
    for (int off = 1; off < 64; off <<= 1) {
        float mo = __shfl_xor(m, off), so = __shfl_xor(s, off);
        float nm = fmaxf(m, mo);
        s = s * __expf(m - nm) + so * __expf(mo - nm);
        m = nm;
    }
    __shared__ float pm[4], ps2[4];
    if ((tid & 63) == 0) { pm[tid >> 6] = m; ps2[tid >> 6] = s; }
    __syncthreads();
    if (tid == 0) {
        float M = fmaxf(fmaxf(pm[0], pm[1]), fmaxf(pm[2], pm[3]));
        float S = ps2[0] * __expf(pm[0] - M) + ps2[1] * __expf(pm[1] - M)
                + ps2[2] * __expf(pm[2] - M) + ps2[3] * __expf(pm[3] - M);
        int tg = targets[t];
        float v = 0.0f;
        if (tg >= 0) v = (M + logf(S)) - logits[(size_t)t * V_DIM + tg];
        nll[t] = v;
    }
}

__global__ void loss_reduce_kernel(const float* __restrict__ nll, float* __restrict__ out)
{
    int tid = threadIdx.x;
    float s = 0.0f;
    for (int i = tid; i < NTOK; i += 256) s += nll[i];
#pragma unroll
    for (int off = 1; off < 64; off <<= 1) s += __shfl_xor(s, off);
    __shared__ float p[4];
    if ((tid & 63) == 0) p[tid >> 6] = s;
    __syncthreads();
    if (tid == 0) out[0] = (p[0] + p[1] + p[2] + p[3]) * (1.0f / NTOK);
}

// ---------------- host launcher ----------------
extern "C" void kernel_launch(void* const* d_in, const int* in_sizes, int n_in,
                              void* d_out, int out_size, void* d_ws, size_t ws_size,
                              hipStream_t stream)
{
    const int*   ids   = (const int*)d_in[0];
    const int*   tgt   = (const int*)d_in[1];
    const float* emb   = (const float*)d_in[2];
    const float* ln_w  = (const float*)d_in[3];
    const float* ln_b  = (const float*)d_in[4];
    const float* inw   = (const float*)d_in[5];
    const float* convw = (const float*)d_in[6];
    const float* convb = (const float*)d_in[7];
    const float* xw    = (const float*)d_in[8];
    const float* dtw   = (const float*)d_in[9];
    const float* dtb   = (const float*)d_in[10];
    const float* alog  = (const float*)d_in[11];
    const float* dpar  = (const float*)d_in[12];
    const float* outw  = (const float*)d_in[13];
    const float* flnw  = (const float*)d_in[14];
    const float* flnb  = (const float*)d_in[15];
    float* logits = (float*)d_out;
    float* lossp  = logits + (size_t)NTOK * V_DIM;

    char* wsp = (char*)d_ws;
    size_t off = 0;
    auto alloc = [&](size_t bytes) -> void* {
        void* p = wsp + off;
        off += (bytes + 255) & ~(size_t)255;
        return p;
    };
    bf16*  emb_bf  = (bf16*)alloc((size_t)V_DIM * E_DIM * 2);           // 65.5 MB
    bf16*  winl    = (bf16*)alloc((size_t)2 * DI_DIM * E_DIM * 2);      // 8.4 MB (per-layer)
    bf16*  woutl   = (bf16*)alloc((size_t)E_DIM * DI_DIM * 2);          // 4.2 MB
    bf16*  wdtl    = (bf16*)alloc((size_t)DI_DIM * DTR_DIM * 2);        // 0.26 MB
    float* x       = (float*)alloc((size_t)NTOK * E_DIM * 4);
    bf16*  h_bf    = (bf16*)alloc((size_t)NTOK * E_DIM * 2);
    float* xzb     = (float*)alloc((size_t)NTOK * 2 * DI_DIM * 4);
    float* ub      = (float*)alloc((size_t)NTOK * DI_DIM * 4);
    float* xdbl    = (float*)alloc((size_t)NTOK * 96 * 4);
    bf16*  dt_bf   = (bf16*)alloc((size_t)NTOK * DTR_DIM * 2);
    float* deltab  = (float*)alloc((size_t)NTOK * DI_DIM * 4);
    bf16*  y_bf    = (bf16*)alloc((size_t)NTOK * DI_DIM * 2);
    bf16*  xf_bf   = (bf16*)alloc((size_t)NTOK * E_DIM * 2);
    float* nll     = (float*)alloc((size_t)NTOK * 4);
    float* Pbuf    = (float*)alloc((size_t)NBATCH * NC * DI_DIM * NS_DIM * 4);
    float* Sbuf    = (float*)alloc((size_t)NBATCH * NC * DI_DIM * NS_DIM * 4);
    float* Hstart  = (float*)alloc((size_t)NBATCH * NC * DI_DIM * NS_DIM * 4);
    if (off > ws_size) return;

    auto cast = [&](const float* in, bf16* out, size_t n) {
        int n4 = (int)(n / 4);
        int grid = (n4 + 255) / 256; if (grid > 4096) grid = 4096;
        cast_f32_to_bf16<<<grid, 256, 0, stream>>>(in, out, n4);
    };
    cast(emb, emb_bf, (size_t)V_DIM * E_DIM);
    embed_kernel<<<NTOK, 256, 0, stream>>>(ids, emb, x);

    for (int l = 0; l < NL_DIM; ++l) {
        cast(inw  + (size_t)l * 2 * DI_DIM * E_DIM, winl,  (size_t)2 * DI_DIM * E_DIM);
        cast(outw + (size_t)l * E_DIM * DI_DIM,     woutl, (size_t)E_DIM * DI_DIM);
        cast(dtw  + (size_t)l * DI_DIM * DTR_DIM,   wdtl,  (size_t)DI_DIM * DTR_DIM);

        ln_kernel<<<NTOK, 256, 0, stream>>>(x, ln_w + l * E_DIM, ln_b + l * E_DIM, h_bf);
        // xz[1024,4096] = h @ in_w^T         grid: (rows, cols)
        gemm_bt<0><<<dim3(NTOK / 128, 2 * DI_DIM / 128), 256, 0, stream>>>(
            h_bf, winl, xzb, NTOK, 2 * DI_DIM, E_DIM, E_DIM, E_DIM, 2 * DI_DIM, nullptr);
        conv_silu_kernel<<<(NTOK * DI_DIM / 4) / 256, 256, 0, stream>>>(
            xzb, convw + l * DI_DIM * DC_DIM, convb + l * DI_DIM, ub);
        xproj_kernel<<<NTOK / 8, 128, 0, stream>>>(ub, xw + (size_t)l * 96 * DI_DIM, xdbl, dt_bf);
        // delta[1024,2048] = softplus(dt @ dtw^T + dtb)
        gemm_bt<2><<<dim3(NTOK / 128, DI_DIM / 128), 256, 0, stream>>>(
            dt_bf, wdtl, deltab, NTOK, DI_DIM, DTR_DIM, DTR_DIM, DTR_DIM, DI_DIM, dtb + l * DI_DIM);
        // chunked scan
        scan_phase_a<<<NBATCH * (DI_DIM / 16) * NC, 256, 0, stream>>>(
            deltab, xdbl, ub, alog + (size_t)l * DI_DIM * NS_DIM, Pbuf, Sbuf);
        scan_combine<<<NBATCH * DI_DIM * NS_DIM / 256, 256, 0, stream>>>(Pbuf, Sbuf, Hstart);
        scan_phase_c<<<NBATCH * (DI_DIM / 16) * NC, 256, 0, stream>>>(
            deltab, xdbl, ub, xzb, alog + (size_t)l * DI_DIM * NS_DIM, dpar + l * DI_DIM,
            Hstart, y_bf);
        // x += y @ out_w^T
        gemm_bt<1><<<dim3(NTOK / 128, E_DIM / 128), 256, 0, stream>>>(
            y_bf, woutl, x, NTOK, E_DIM, DI_DIM, DI_DIM, DI_DIM, E_DIM, nullptr);
    }
    ln_kernel<<<NTOK, 256, 0, stream>>>(x, flnw, flnb, xf_bf);
    // logits = x_f @ emb^T
    gemm_bt<0><<<dim3(NTOK / 128, V_DIM / 128), 256, 0, stream>>>(
        xf_bf, emb_bf, logits, NTOK, V_DIM, E_DIM, E_DIM, E_DIM, V_DIM, nullptr);
    lse_nll_kernel<<<NTOK, 256, 0, stream>>>(logits, tgt, nll);
    loss_reduce_kernel<<<1, 256, 0, stream>>>(nll, lossp);
}

// Round 4
// 1090.907 us; speedup vs baseline: 1.4713x; 1.1772x over previous
//
#include <hip/hip_runtime.h>
#include <cstdint>
#include <cstddef>

#define L_SEQ 512
#define NBATCH 2
#define NTOK 1024          // B*L
#define E_DIM 1024
#define V_DIM 32000
#define DI_DIM 2048
#define NS_DIM 16
#define DTR_DIM 64
#define DC_DIM 4
#define NL_DIM 4
#define NC 8               // time chunks for parallel scan
#define LC (L_SEQ / NC)    // 64

typedef __bf16 bf16;
typedef __bf16 bf16x8 __attribute__((ext_vector_type(8)));
typedef __bf16 bf16x4 __attribute__((ext_vector_type(4)));
typedef float  f32x4  __attribute__((ext_vector_type(4)));

// async global->LDS, 16B per lane. LDS dest must be wave-uniform base (+lane*16 implicit).
__device__ __forceinline__ void gload_lds16(const void* g, void* l)
{
    __builtin_amdgcn_global_load_lds((const __attribute__((address_space(1))) uint32_t*)g,
                                     (__attribute__((address_space(3))) uint32_t*)l, 16, 0, 0);
}

// ---------------- cast f32 -> bf16 (grid-stride, x4) ----------------
__global__ void cast_f32_to_bf16(const float* __restrict__ in, bf16* __restrict__ out, int n4)
{
    int stride = gridDim.x * blockDim.x;
    for (int i = blockIdx.x * blockDim.x + threadIdx.x; i < n4; i += stride) {
        f32x4 v = ((const f32x4*)in)[i];
        bf16x4 o;
        o[0] = (bf16)v[0]; o[1] = (bf16)v[1]; o[2] = (bf16)v[2]; o[3] = (bf16)v[3];
        ((bf16x4*)out)[i] = o;
    }
}

// fused 3-tensor cast (one launch per layer: in_w, out_w, dt_w)
__global__ void cast3_kernel(const float* __restrict__ a, bf16* __restrict__ oa, int na4,
                             const float* __restrict__ b, bf16* __restrict__ ob, int nb4,
                             const float* __restrict__ c, bf16* __restrict__ oc, int nc4)
{
    int stride = gridDim.x * blockDim.x;
    int tot = na4 + nb4 + nc4;
    for (int i = blockIdx.x * blockDim.x + threadIdx.x; i < tot; i += stride) {
        const float* src; bf16* dst; int k = i;
        if (k < na4) { src = a; dst = oa; }
        else if ((k -= na4) < nb4) { src = b; dst = ob; }
        else { k -= nb4; src = c; dst = oc; }
        f32x4 v = ((const f32x4*)src)[k];
        bf16x4 o;
        o[0] = (bf16)v[0]; o[1] = (bf16)v[1]; o[2] = (bf16)v[2]; o[3] = (bf16)v[3];
        ((bf16x4*)dst)[k] = o;
    }
}

// ---------------- embedding gather ----------------
__global__ void embed_kernel(const int* __restrict__ ids, const float* __restrict__ emb,
                             float* __restrict__ x)
{
    int t = blockIdx.x;
    int id = ids[t];
    ((f32x4*)(x + (size_t)t * E_DIM))[threadIdx.x] =
        ((const f32x4*)(emb + (size_t)id * E_DIM))[threadIdx.x];
}

// ---------------- LayerNorm (row=1024), bf16 out ----------------
__global__ void ln_kernel(const float* __restrict__ x, const float* __restrict__ w,
                          const float* __restrict__ b, bf16* __restrict__ out)
{
    int t = blockIdx.x;
    int tid = threadIdx.x;
    f32x4 v = ((const f32x4*)(x + (size_t)t * E_DIM))[tid];
    float s  = v[0] + v[1] + v[2] + v[3];
    float sq = v[0]*v[0] + v[1]*v[1] + v[2]*v[2] + v[3]*v[3];
#pragma unroll
    for (int off = 1; off < 64; off <<= 1) { s += __shfl_xor(s, off); sq += __shfl_xor(sq, off); }
    __shared__ float ps[4], pq[4];
    if ((tid & 63) == 0) { ps[tid >> 6] = s; pq[tid >> 6] = sq; }
    __syncthreads();
    float S  = ps[0] + ps[1] + ps[2] + ps[3];
    float SQ = pq[0] + pq[1] + pq[2] + pq[3];
    float mu  = S * (1.0f / E_DIM);
    float var = SQ * (1.0f / E_DIM) - mu * mu;
    float rs  = rsqrtf(var + 1e-5f);
    f32x4 wv = ((const f32x4*)w)[tid];
    f32x4 bv = ((const f32x4*)b)[tid];
    bf16x4 o;
#pragma unroll
    for (int i = 0; i < 4; ++i) o[i] = (bf16)((v[i] - mu) * rs * wv[i] + bv[i]);
    ((bf16x4*)(out + (size_t)t * E_DIM))[tid] = o;
}

// ---------------- MFMA bf16 GEMM: C[M,N] = A[M,K] * B[N,K]^T ----------------
// Templated tile BM x BN (64/128), BK=32, 256 threads = 4 waves in 2x2 grid;
// wave tile (BM/2)x(BN/2). global_load_lds staging. 1-D grid with XCD-chunked
// swizzle: xcd = pid&7 owns a contiguous col-chunk, rows-fastest within, so all
// row-blocks sharing one B-tile land on ONE XCD's L2.
// MODE 0: store; MODE 1: C += (residual); MODE 2: C = softplus(acc + bias[col])
template<int BM, int BN, int MODE>
__global__ __launch_bounds__(256) void gemm_bt(const bf16* __restrict__ A, const bf16* __restrict__ B,
                                               float* __restrict__ C, int K,
                                               int lda, int ldb, int ldc,
                                               const float* __restrict__ bias,
                                               int RB, int CB, int CBpad)
{
    int pid = blockIdx.x;
    int xcd = pid & 7;
    int j   = pid >> 3;
    int cpx = CBpad >> 3;
    int rb  = j % RB;
    int cb  = xcd * cpx + j / RB;
    if (cb >= CB) return;

    __shared__ __align__(16) bf16 As[BM * 32];
    __shared__ __align__(16) bf16 Bs[BN * 32];
    int tid  = threadIdx.x;
    int lane = tid & 63;
    int wid  = tid >> 6;
    int wr = wid >> 1, wc = wid & 1;
    int li = lane & 15, lg = lane >> 4;
    const bf16* Ablk = A + (size_t)(rb * BM) * lda;
    const bf16* Bblk = B + (size_t)(cb * BN) * ldb;
    constexpr int MR  = BM / 32;          // 16-row fragments per wave
    constexpr int NR  = BN / 32;
    constexpr int TOT = (BM + BN) * 4;    // 16B lane-ops per K-step
    f32x4 acc[MR][NR] = {};
    for (int k0 = 0; k0 < K; k0 += 32) {
        __syncthreads();
#pragma unroll
        for (int it = 0; it < TOT / 256; ++it) {
            int wbase = it * 256 + wid * 64;      // wave-uniform (BM*4 is a multiple of 64)
            int idx   = wbase + lane;
            if (wbase < BM * 4) {
                int row = idx >> 2, seg = idx & 3;
                gload_lds16(Ablk + (size_t)row * lda + k0 + seg * 8, As + (size_t)wbase * 8);
            } else {
                int bb  = wbase - BM * 4;
                int bi  = bb + lane;
                int row = bi >> 2, seg = bi & 3;
                gload_lds16(Bblk + (size_t)row * ldb + k0 + seg * 8, Bs + (size_t)bb * 8);
            }
        }
        __syncthreads();
        bf16x8 af[MR], bfr[NR];
#pragma unroll
        for (int m = 0; m < MR; ++m) af[m]  = *(const bf16x8*)&As[(wr * (BM/2) + m * 16 + li) * 32 + lg * 8];
#pragma unroll
        for (int n = 0; n < NR; ++n) bfr[n] = *(const bf16x8*)&Bs[(wc * (BN/2) + n * 16 + li) * 32 + lg * 8];
#pragma unroll
        for (int m = 0; m < MR; ++m)
#pragma unroll
            for (int n = 0; n < NR; ++n)
                acc[m][n] = __builtin_amdgcn_mfma_f32_16x16x32_bf16(af[m], bfr[n], acc[m][n], 0, 0, 0);
    }
    int row0 = rb * BM + wr * (BM/2);
    int col0 = cb * BN + wc * (BN/2);
#pragma unroll
    for (int m = 0; m < MR; ++m) {
#pragma unroll
        for (int n = 0; n < NR; ++n) {
            int r = row0 + m * 16 + lg * 4;
            int c = col0 + n * 16 + li;
            float* cp = C + (size_t)r * ldc + c;
#pragma unroll
            for (int q = 0; q < 4; ++q) {
                float v = acc[m][n][q];
                if (MODE == 1) v += cp[(size_t)q * ldc];
                if (MODE == 2) {
                    float z = v + bias[c];
                    v = fmaxf(z, 0.0f) + log1pf(expf(-fabsf(z)));
                }
                cp[(size_t)q * ldc] = v;
            }
        }
    }
}

// launch helper: 1-D swizzled grid
template<int BM, int BN, int MODE>
static void launch_gemm(const bf16* A, const bf16* B, float* C, int M, int N, int K,
                        int lda, int ldb, int ldc, const float* bias, hipStream_t stream)
{
    int RB = M / BM;
    int CB = (N + BN - 1) / BN;
    int CBpad = (CB + 7) & ~7;
    gemm_bt<BM, BN, MODE><<<RB * CBpad, 256, 0, stream>>>(A, B, C, K, lda, ldb, ldc, bias, RB, CB, CBpad);
}

// ---------------- causal depthwise conv (DC=4) + SiLU ----------------
__global__ void conv_silu_kernel(const float* __restrict__ xz, const float* __restrict__ cw,
                                 const float* __restrict__ cb, float* __restrict__ u)
{
    int gid = blockIdx.x * 256 + threadIdx.x;   // 0 .. NTOK*DI/4-1
    int t  = gid >> 9;                          // /(DI/4)
    int d4 = (gid & 511) << 2;
    int l  = t & (L_SEQ - 1);
    f32x4 acc;
    acc[0] = cb[d4]; acc[1] = cb[d4 + 1]; acc[2] = cb[d4 + 2]; acc[3] = cb[d4 + 3];
    f32x4 w0 = ((const f32x4*)cw)[d4 + 0];
    f32x4 w1 = ((const f32x4*)cw)[d4 + 1];
    f32x4 w2 = ((const f32x4*)cw)[d4 + 2];
    f32x4 w3 = ((const f32x4*)cw)[d4 + 3];
#pragma unroll
    for (int k = 0; k < 4; ++k) {
        if (l + k >= 3) {
            f32x4 uv = *(const f32x4*)(xz + (size_t)(t + k - 3) * (2 * DI_DIM) + d4);
            acc[0] += w0[k] * uv[0];
            acc[1] += w1[k] * uv[1];
            acc[2] += w2[k] * uv[2];
            acc[3] += w3[k] * uv[3];
        }
    }
    f32x4 o;
#pragma unroll
    for (int i = 0; i < 4; ++i) { float a = acc[i]; o[i] = a / (1.0f + __expf(-a)); }
    *(f32x4*)(u + (size_t)t * DI_DIM + d4) = o;
}

// ---------------- x_proj: xdbl[1024,96] = u[1024,2048] @ xw[96,2048]^T (f32) ----------------
__global__ void xproj_kernel(const float* __restrict__ u, const float* __restrict__ xw,
                             float* __restrict__ xdbl, bf16* __restrict__ dt_bf)
{
    int t0 = blockIdx.x * 8;
    int f  = threadIdx.x;
    __shared__ __align__(16) float su[8][256];
    float acc[8] = {0,0,0,0,0,0,0,0};
    for (int kc = 0; kc < DI_DIM; kc += 256) {
        __syncthreads();
#pragma unroll
        for (int j = 0; j < 4; ++j) {
            int idx = j * 128 + threadIdx.x;    // 0..511 float4 index
            int tt = idx >> 6;
            int c4 = (idx & 63) * 4;
            *(f32x4*)&su[tt][c4] = *(const f32x4*)&u[(size_t)(t0 + tt) * DI_DIM + kc + c4];
        }
        __syncthreads();
        if (f < 96) {
            for (int kk = 0; kk < 256; kk += 4) {
                f32x4 wv = *(const f32x4*)&xw[(size_t)f * DI_DIM + kc + kk];
#pragma unroll
                for (int tt = 0; tt < 8; ++tt) {
                    f32x4 uv = *(f32x4*)&su[tt][kk];
                    acc[tt] += wv[0]*uv[0] + wv[1]*uv[1] + wv[2]*uv[2] + wv[3]*uv[3];
                }
            }
        }
    }
    if (f < 96) {
#pragma unroll
        for (int tt = 0; tt < 8; ++tt) {
            xdbl[(size_t)(t0 + tt) * 96 + f] = acc[tt];
            if (f < 64) dt_bf[(size_t)(t0 + tt) * DTR_DIM + f] = (bf16)acc[tt];
        }
    }
}

// ---------------- chunked selective scan ----------------
__global__ __launch_bounds__(256) void scan_phase_a(
        const float* __restrict__ delta, const float* __restrict__ xdbl,
        const float* __restrict__ u, const float* __restrict__ A_log,
        float* __restrict__ Pbuf, float* __restrict__ Sbuf)
{
    int tid = threadIdx.x;
    int c   = blockIdx.x & (NC - 1);
    int dblk= (blockIdx.x >> 3) & 127;
    int b   = blockIdx.x >> 10;
    int d0  = dblk << 4;
    int n = tid & 15, dl = tid >> 4;
    int d = d0 + dl;
    float Ac = -expf(A_log[(size_t)d * NS_DIM + n]);
    float h = 0.0f, P = 1.0f;
    __shared__ float s_dlt[32][16], s_u[32][16], s_B[32][16];
    int tt0 = tid >> 4, cc = tid & 15;
    int tbase = b * L_SEQ + c * LC;
    for (int t0 = 0; t0 < LC; t0 += 32) {
        __syncthreads();
#pragma unroll
        for (int j = 0; j < 2; ++j) {
            int tt = j * 16 + tt0;
            size_t trow = (size_t)(tbase + t0 + tt);
            s_dlt[tt][cc] = delta[trow * DI_DIM + d0 + cc];
            s_u[tt][cc]   = u[trow * DI_DIM + d0 + cc];
            s_B[tt][cc]   = xdbl[trow * 96 + 64 + cc];
        }
        __syncthreads();
#pragma unroll
        for (int t = 0; t < 32; ++t) {
            float dlt = s_dlt[t][dl];
            float dA  = __expf(dlt * Ac);
            h = fmaf(dA, h, dlt * s_B[t][n] * s_u[t][dl]);
            P *= dA;
        }
    }
    size_t oi = (((size_t)(b * NC + c) * DI_DIM) + d) * NS_DIM + n;
    Pbuf[oi] = P;
    Sbuf[oi] = h;
}

__global__ void scan_combine(const float* __restrict__ Pbuf, const float* __restrict__ Sbuf,
                             float* __restrict__ Hstart)
{
    int i  = blockIdx.x * 256 + threadIdx.x;    // (b, d, n) flat
    int b  = i >> 15;                            // / (DI*NS)
    int dn = i & 32767;
    float h = 0.0f;
#pragma unroll
    for (int c = 0; c < NC; ++c) {
        size_t oi = ((size_t)(b * NC + c) * (DI_DIM * NS_DIM)) + dn;
        Hstart[oi] = h;
        h = fmaf(Pbuf[oi], h, Sbuf[oi]);
    }
}

__global__ __launch_bounds__(256) void scan_phase_c(
        const float* __restrict__ delta, const float* __restrict__ xdbl,
        const float* __restrict__ u, const float* __restrict__ xz,
        const float* __restrict__ A_log, const float* __restrict__ D_par,
        const float* __restrict__ Hstart, bf16* __restrict__ y)
{
    int tid = threadIdx.x;
    int c   = blockIdx.x & (NC - 1);
    int dblk= (blockIdx.x >> 3) & 127;
    int b   = blockIdx.x >> 10;
    int d0  = dblk << 4;
    int n = tid & 15, dl = tid >> 4;
    int d = d0 + dl;
    float Ac = -expf(A_log[(size_t)d * NS_DIM + n]);
    float Dp = D_par[d];
    float h = Hstart[(((size_t)(b * NC + c) * DI_DIM) + d) * NS_DIM + n];
    __shared__ float s_dlt[32][16], s_u[32][16], s_res[32][16], s_B[32][16], s_C[32][16];
    __shared__ bf16  s_y[32][16];
    int tt0 = tid >> 4, cc = tid & 15;
    int tbase = b * L_SEQ + c * LC;
    for (int t0 = 0; t0 < LC; t0 += 32) {
        __syncthreads();
#pragma unroll
        for (int j = 0; j < 2; ++j) {
            int tt = j * 16 + tt0;
            size_t trow = (size_t)(tbase + t0 + tt);
            s_dlt[tt][cc] = delta[trow * DI_DIM + d0 + cc];
            s_u[tt][cc]   = u[trow * DI_DIM + d0 + cc];
            s_res[tt][cc] = xz[trow * (2 * DI_DIM) + DI_DIM + d0 + cc];
            s_B[tt][cc]   = xdbl[trow * 96 + 64 + cc];
            s_C[tt][cc]   = xdbl[trow * 96 + 80 + cc];
        }
        __syncthreads();
#pragma unroll
        for (int t = 0; t < 32; ++t) {
            float dlt = s_dlt[t][dl];
            float uu  = s_u[t][dl];
            float dA  = __expf(dlt * Ac);
            float dBu = dlt * s_B[t][n] * uu;
            h = fmaf(dA, h, dBu);
            float yp = h * s_C[t][n];
            yp += __shfl_xor(yp, 1);
            yp += __shfl_xor(yp, 2);
            yp += __shfl_xor(yp, 4);
            yp += __shfl_xor(yp, 8);
            if (n == 0) {
                float res = s_res[t][dl];
                float yv  = fmaf(uu, Dp, yp) * (res / (1.0f + __expf(-res)));
                s_y[t][dl] = (bf16)yv;
            }
        }
        __syncthreads();
#pragma unroll
        for (int j = 0; j < 2; ++j) {
            int tt = j * 16 + tt0;
            size_t trow = (size_t)(tbase + t0 + tt);
            y[trow * DI_DIM + d0 + cc] = s_y[tt][cc];
        }
    }
}

// ---------------- per-token online logsumexp + NLL (single pass) ----------------
__global__ void lse_nll_kernel(const float* __restrict__ logits, const int* __restrict__ targets,
                               float* __restrict__ nll)
{
    int t = blockIdx.x, tid = threadIdx.x;
    const f32x4* row = (const f32x4*)(logits + (size_t)t * V_DIM);
    float m = -1e30f, s = 0.0f;
    for (int i = tid; i < V_DIM / 4; i += 256) {
        f32x4 v = row[i];
        float m4 = fmaxf(fmaxf(v[0], v[1]), fmaxf(v[2], v[3]));
        if (m4 > m) { s *= __expf(m - m4); m = m4; }   // defer-max: rescale only on growth
        s += __expf(v[0] - m) + __expf(v[1] - m) + __expf(v[2] - m) + __expf(v[3] - m);
    }
#pragma unroll
    for (int off = 1; off < 64; off <<= 1) {
        float mo = __shfl_xor(m, off), so = __shfl_xor(s, off);
        float nm = fmaxf(m, mo);
        s = s * __expf(m - nm) + so * __expf(mo - nm);
        m = nm;
    }
    __shared__ float pm[4], ps2[4];
    if ((tid & 63) == 0) { pm[tid >> 6] = m; ps2[tid >> 6] = s; }
    __syncthreads();
    if (tid == 0) {
        float M = fmaxf(fmaxf(pm[0], pm[1]), fmaxf(pm[2], pm[3]));
        float S = ps2[0] * __expf(pm[0] - M) + ps2[1] * __expf(pm[1] - M)
                + ps2[2] * __expf(pm[2] - M) + ps2[3] * __expf(pm[3] - M);
        int tg = targets[t];
        float v = 0.0f;
        if (tg >= 0) v = (M + logf(S)) - logits[(size_t)t * V_DIM + tg];
        nll[t] = v;
    }
}

__global__ void loss_reduce_kernel(const float* __restrict__ nll, float* __restrict__ out)
{
    int tid = threadIdx.x;
    float s = 0.0f;
    for (int i = tid; i < NTOK; i += 256) s += nll[i];
#pragma unroll
    for (int off = 1; off < 64; off <<= 1) s += __shfl_xor(s, off);
    __shared__ float p[4];
    if ((tid & 63) == 0) p[tid >> 6] = s;
    __syncthreads();
    if (tid == 0) out[0] = (p[0] + p[1] + p[2] + p[3]) * (1.0f / NTOK);
}

// ---------------- host launcher ----------------
extern "C" void kernel_launch(void* const* d_in, const int* in_sizes, int n_in,
                              void* d_out, int out_size, void* d_ws, size_t ws_size,
                              hipStream_t stream)
{
    const int*   ids   = (const int*)d_in[0];
    const int*   tgt   = (const int*)d_in[1];
    const float* emb   = (const float*)d_in[2];
    const float* ln_w  = (const float*)d_in[3];
    const float* ln_b  = (const float*)d_in[4];
    const float* inw   = (const float*)d_in[5];
    const float* convw = (const float*)d_in[6];
    const float* convb = (const float*)d_in[7];
    const float* xw    = (const float*)d_in[8];
    const float* dtw   = (const float*)d_in[9];
    const float* dtb   = (const float*)d_in[10];
    const float* alog  = (const float*)d_in[11];
    const float* dpar  = (const float*)d_in[12];
    const float* outw  = (const float*)d_in[13];
    const float* flnw  = (const float*)d_in[14];
    const float* flnb  = (const float*)d_in[15];
    float* logits = (float*)d_out;
    float* lossp  = logits + (size_t)NTOK * V_DIM;

    char* wsp = (char*)d_ws;
    size_t off = 0;
    auto alloc = [&](size_t bytes) -> void* {
        void* p = wsp + off;
        off += (bytes + 255) & ~(size_t)255;
        return p;
    };
    bf16*  emb_bf  = (bf16*)alloc((size_t)V_DIM * E_DIM * 2);           // 65.5 MB
    bf16*  winl    = (bf16*)alloc((size_t)2 * DI_DIM * E_DIM * 2);      // 8.4 MB (per-layer)
    bf16*  woutl   = (bf16*)alloc((size_t)E_DIM * DI_DIM * 2);          // 4.2 MB
    bf16*  wdtl    = (bf16*)alloc((size_t)DI_DIM * DTR_DIM * 2);        // 0.26 MB
    float* x       = (float*)alloc((size_t)NTOK * E_DIM * 4);
    bf16*  h_bf    = (bf16*)alloc((size_t)NTOK * E_DIM * 2);
    float* xzb     = (float*)alloc((size_t)NTOK * 2 * DI_DIM * 4);
    float* ub      = (float*)alloc((size_t)NTOK * DI_DIM * 4);
    float* xdbl    = (float*)alloc((size_t)NTOK * 96 * 4);
    bf16*  dt_bf   = (bf16*)alloc((size_t)NTOK * DTR_DIM * 2);
    float* deltab  = (float*)alloc((size_t)NTOK * DI_DIM * 4);
    bf16*  y_bf    = (bf16*)alloc((size_t)NTOK * DI_DIM * 2);
    bf16*  xf_bf   = (bf16*)alloc((size_t)NTOK * E_DIM * 2);
    float* nll     = (float*)alloc((size_t)NTOK * 4);
    float* Pbuf    = (float*)alloc((size_t)NBATCH * NC * DI_DIM * NS_DIM * 4);
    float* Sbuf    = (float*)alloc((size_t)NBATCH * NC * DI_DIM * NS_DIM * 4);
    float* Hstart  = (float*)alloc((size_t)NBATCH * NC * DI_DIM * NS_DIM * 4);
    if (off > ws_size) return;

    {   // emb cast (once per call)
        int n4 = (int)((size_t)V_DIM * E_DIM / 4);
        cast_f32_to_bf16<<<4096, 256, 0, stream>>>(emb, emb_bf, n4);
    }
    embed_kernel<<<NTOK, 256, 0, stream>>>(ids, emb, x);

    for (int l = 0; l < NL_DIM; ++l) {
        // fused per-layer weight cast: in_w, out_w, dt_w
        cast3_kernel<<<2048, 256, 0, stream>>>(
            inw  + (size_t)l * 2 * DI_DIM * E_DIM, winl,  (int)((size_t)2 * DI_DIM * E_DIM / 4),
            outw + (size_t)l * E_DIM * DI_DIM,     woutl, (int)((size_t)E_DIM * DI_DIM / 4),
            dtw  + (size_t)l * DI_DIM * DTR_DIM,   wdtl,  (int)((size_t)DI_DIM * DTR_DIM / 4));

        ln_kernel<<<NTOK, 256, 0, stream>>>(x, ln_w + l * E_DIM, ln_b + l * E_DIM, h_bf);
        // xz[1024,4096] = h @ in_w^T    (128x64 tiles -> 512 blocks, 2/CU)
        launch_gemm<128, 64, 0>(h_bf, winl, xzb, NTOK, 2 * DI_DIM, E_DIM,
                                E_DIM, E_DIM, 2 * DI_DIM, nullptr, stream);
        conv_silu_kernel<<<(NTOK * DI_DIM / 4) / 256, 256, 0, stream>>>(
            xzb, convw + l * DI_DIM * DC_DIM, convb + l * DI_DIM, ub);
        xproj_kernel<<<NTOK / 8, 128, 0, stream>>>(ub, xw + (size_t)l * 96 * DI_DIM, xdbl, dt_bf);
        // delta = softplus(dt @ dtw^T + dtb)   (64x64 tiles -> 512 blocks)
        launch_gemm<64, 64, 2>(dt_bf, wdtl, deltab, NTOK, DI_DIM, DTR_DIM,
                               DTR_DIM, DTR_DIM, DI_DIM, dtb + l * DI_DIM, stream);
        // chunked scan
        scan_phase_a<<<NBATCH * (DI_DIM / 16) * NC, 256, 0, stream>>>(
            deltab, xdbl, ub, alog + (size_t)l * DI_DIM * NS_DIM, Pbuf, Sbuf);
        scan_combine<<<NBATCH * DI_DIM * NS_DIM / 256, 256, 0, stream>>>(Pbuf, Sbuf, Hstart);
        scan_phase_c<<<NBATCH * (DI_DIM / 16) * NC, 256, 0, stream>>>(
            deltab, xdbl, ub, xzb, alog + (size_t)l * DI_DIM * NS_DIM, dpar + l * DI_DIM,
            Hstart, y_bf);
        // x += y @ out_w^T              (64x64 tiles -> 256 blocks, all CUs busy)
        launch_gemm<64, 64, 1>(y_bf, woutl, x, NTOK, E_DIM, DI_DIM,
                               DI_DIM, DI_DIM, E_DIM, nullptr, stream);
    }
    ln_kernel<<<NTOK, 256, 0, stream>>>(x, flnw, flnb, xf_bf);
    // logits = x_f @ emb^T              (128x128 tiles, XCD-chunked cols)
    launch_gemm<128, 128, 0>(xf_bf, emb_bf, logits, NTOK, V_DIM, E_DIM,
                             E_DIM, E_DIM, V_DIM, nullptr, stream);
    lse_nll_kernel<<<NTOK, 256, 0, stream>>>(logits, tgt, nll);
    loss_reduce_kernel<<<1, 256, 0, stream>>>(nll, lossp);
}

// Round 5
// 919.866 us; speedup vs baseline: 1.7449x; 1.1859x over previous
//
#include <hip/hip_runtime.h>
#include <cstdint>
#include <cstddef>

#define L_SEQ 512
#define NBATCH 2
#define NTOK 1024          // B*L
#define E_DIM 1024
#define V_DIM 32000
#define DI_DIM 2048
#define NS_DIM 16
#define DTR_DIM 64
#define DC_DIM 4
#define NL_DIM 4
#define NC 8               // time chunks for parallel scan
#define LC (L_SEQ / NC)    // 64
#define CB_LOG 250         // logits col-blocks (32000/128)

typedef __bf16 bf16;
typedef __bf16 bf16x8 __attribute__((ext_vector_type(8)));
typedef __bf16 bf16x4 __attribute__((ext_vector_type(4)));
typedef float  f32x4  __attribute__((ext_vector_type(4)));

// async global->LDS, 16B per lane. LDS dest must be wave-uniform base (+lane*16 implicit).
__device__ __forceinline__ void gload_lds16(const void* g, void* l)
{
    __builtin_amdgcn_global_load_lds((const __attribute__((address_space(1))) uint32_t*)g,
                                     (__attribute__((address_space(3))) uint32_t*)l, 16, 0, 0);
}

__device__ __forceinline__ float softplusf(float z)
{
    return fmaxf(z, 0.0f) + log1pf(expf(-fabsf(z)));
}

// ---------------- cast f32 -> bf16 (grid-stride, x4) ----------------
__global__ void cast_f32_to_bf16(const float* __restrict__ in, bf16* __restrict__ out, int n4)
{
    int stride = gridDim.x * blockDim.x;
    for (int i = blockIdx.x * blockDim.x + threadIdx.x; i < n4; i += stride) {
        f32x4 v = ((const f32x4*)in)[i];
        bf16x4 o;
        o[0] = (bf16)v[0]; o[1] = (bf16)v[1]; o[2] = (bf16)v[2]; o[3] = (bf16)v[3];
        ((bf16x4*)out)[i] = o;
    }
}

// fused 2-tensor cast (per layer: in_w, out_w)
__global__ void cast2_kernel(const float* __restrict__ a, bf16* __restrict__ oa, int na4,
                             const float* __restrict__ b, bf16* __restrict__ ob, int nb4)
{
    int stride = gridDim.x * blockDim.x;
    int tot = na4 + nb4;
    for (int i = blockIdx.x * blockDim.x + threadIdx.x; i < tot; i += stride) {
        const float* src; bf16* dst; int k = i;
        if (k < na4) { src = a; dst = oa; }
        else { k -= na4; src = b; dst = ob; }
        f32x4 v = ((const f32x4*)src)[k];
        bf16x4 o;
        o[0] = (bf16)v[0]; o[1] = (bf16)v[1]; o[2] = (bf16)v[2]; o[3] = (bf16)v[3];
        ((bf16x4*)dst)[k] = o;
    }
}

// ---------------- embedding gather ----------------
__global__ void embed_kernel(const int* __restrict__ ids, const float* __restrict__ emb,
                             float* __restrict__ x)
{
    int t = blockIdx.x;
    int id = ids[t];
    ((f32x4*)(x + (size_t)t * E_DIM))[threadIdx.x] =
        ((const f32x4*)(emb + (size_t)id * E_DIM))[threadIdx.x];
}

// ---------------- LayerNorm (row=1024), bf16 out ----------------
__global__ void ln_kernel(const float* __restrict__ x, const float* __restrict__ w,
                          const float* __restrict__ b, bf16* __restrict__ out)
{
    int t = blockIdx.x;
    int tid = threadIdx.x;
    f32x4 v = ((const f32x4*)(x + (size_t)t * E_DIM))[tid];
    float s  = v[0] + v[1] + v[2] + v[3];
    float sq = v[0]*v[0] + v[1]*v[1] + v[2]*v[2] + v[3]*v[3];
#pragma unroll
    for (int off = 1; off < 64; off <<= 1) { s += __shfl_xor(s, off); sq += __shfl_xor(sq, off); }
    __shared__ float ps[4], pq[4];
    if ((tid & 63) == 0) { ps[tid >> 6] = s; pq[tid >> 6] = sq; }
    __syncthreads();
    float S  = ps[0] + ps[1] + ps[2] + ps[3];
    float SQ = pq[0] + pq[1] + pq[2] + pq[3];
    float mu  = S * (1.0f / E_DIM);
    float var = SQ * (1.0f / E_DIM) - mu * mu;
    float rs  = rsqrtf(var + 1e-5f);
    f32x4 wv = ((const f32x4*)w)[tid];
    f32x4 bv = ((const f32x4*)b)[tid];
    bf16x4 o;
#pragma unroll
    for (int i = 0; i < 4; ++i) o[i] = (bf16)((v[i] - mu) * rs * wv[i] + bv[i]);
    ((bf16x4*)(out + (size_t)t * E_DIM))[tid] = o;
}

// ---------------- MFMA bf16 GEMM: C[M,N] = A[M,K] * B[N,K]^T ----------------
// Tiles BM x BN, BK=32, 256 threads (4 waves 2x2). global_load_lds staging.
// 1-D grid, XCD-chunked col swizzle (all row-blocks of one B-panel on one XCD's L2).
// MODE 0: store; MODE 1: C += (residual);
// MODE 3: store + per-row online (max, sumexp) partials into Pm/Ps[row*256+cb].
template<int BM, int BN, int MODE>
__global__ __launch_bounds__(256) void gemm_bt(const bf16* __restrict__ A, const bf16* __restrict__ B,
                                               float* __restrict__ C, int K,
                                               int lda, int ldb, int ldc,
                                               float* __restrict__ Pm, float* __restrict__ Ps,
                                               int RB, int CB, int CBpad)
{
    int pid = blockIdx.x;
    int xcd = pid & 7;
    int j   = pid >> 3;
    int cpx = CBpad >> 3;
    int rb  = j % RB;
    int cb  = xcd * cpx + j / RB;
    if (cb >= CB) return;

    __shared__ __align__(16) bf16 As[BM * 32];
    __shared__ __align__(16) bf16 Bs[BN * 32];
    int tid  = threadIdx.x;
    int lane = tid & 63;
    int wid  = tid >> 6;
    int wr = wid >> 1, wc = wid & 1;
    int li = lane & 15, lg = lane >> 4;
    const bf16* Ablk = A + (size_t)(rb * BM) * lda;
    const bf16* Bblk = B + (size_t)(cb * BN) * ldb;
    constexpr int MR  = BM / 32;
    constexpr int NR  = BN / 32;
    constexpr int TOT = (BM + BN) * 4;    // 16B lane-ops per K-step
    f32x4 acc[MR][NR] = {};
    for (int k0 = 0; k0 < K; k0 += 32) {
        __syncthreads();
#pragma unroll
        for (int it = 0; it < TOT / 256; ++it) {
            int wbase = it * 256 + wid * 64;
            int idx   = wbase + lane;
            if (wbase < BM * 4) {
                int row = idx >> 2, seg = idx & 3;
                gload_lds16(Ablk + (size_t)row * lda + k0 + seg * 8, As + (size_t)wbase * 8);
            } else {
                int bb  = wbase - BM * 4;
                int bi  = bb + lane;
                int row = bi >> 2, seg = bi & 3;
                gload_lds16(Bblk + (size_t)row * ldb + k0 + seg * 8, Bs + (size_t)bb * 8);
            }
        }
        __syncthreads();
        bf16x8 af[MR], bfr[NR];
#pragma unroll
        for (int m = 0; m < MR; ++m) af[m]  = *(const bf16x8*)&As[(wr * (BM/2) + m * 16 + li) * 32 + lg * 8];
#pragma unroll
        for (int n = 0; n < NR; ++n) bfr[n] = *(const bf16x8*)&Bs[(wc * (BN/2) + n * 16 + li) * 32 + lg * 8];
#pragma unroll
        for (int m = 0; m < MR; ++m)
#pragma unroll
            for (int n = 0; n < NR; ++n)
                acc[m][n] = __builtin_amdgcn_mfma_f32_16x16x32_bf16(af[m], bfr[n], acc[m][n], 0, 0, 0);
    }
    int row0 = rb * BM + wr * (BM/2);
    int col0 = cb * BN + wc * (BN/2);
#pragma unroll
    for (int m = 0; m < MR; ++m) {
#pragma unroll
        for (int n = 0; n < NR; ++n) {
            int r = row0 + m * 16 + lg * 4;
            int c = col0 + n * 16 + li;
            float* cp = C + (size_t)r * ldc + c;
#pragma unroll
            for (int q = 0; q < 4; ++q) {
                float v = acc[m][n][q];
                if (MODE == 1) v += cp[(size_t)q * ldc];
                cp[(size_t)q * ldc] = v;
            }
        }
    }
    if constexpr (MODE == 3) {
        // per-row (max, sumexp) over this block's BN cols -> partial buffers
        __shared__ float lm_s[2][2][BM / 2], ls_s[2][2][BM / 2];
#pragma unroll
        for (int m = 0; m < MR; ++m) {
#pragma unroll
            for (int q = 0; q < 4; ++q) {
                float mx = acc[m][0][q];
#pragma unroll
                for (int n = 1; n < NR; ++n) mx = fmaxf(mx, acc[m][n][q]);
#pragma unroll
                for (int off = 1; off < 16; off <<= 1) mx = fmaxf(mx, __shfl_xor(mx, off));
                float sv = 0.0f;
#pragma unroll
                for (int n = 0; n < NR; ++n) sv += __expf(acc[m][n][q] - mx);
#pragma unroll
                for (int off = 1; off < 16; off <<= 1) sv += __shfl_xor(sv, off);
                if (li == 0) {
                    int rl = m * 16 + lg * 4 + q;
                    lm_s[wr][wc][rl] = mx;
                    ls_s[wr][wc][rl] = sv;
                }
            }
        }
        __syncthreads();
        if (tid < BM) {
            int wrh = tid >> 6, rl = tid & 63;
            float m0 = lm_s[wrh][0][rl], m1 = lm_s[wrh][1][rl];
            float M  = fmaxf(m0, m1);
            float S  = ls_s[wrh][0][rl] * __expf(m0 - M) + ls_s[wrh][1][rl] * __expf(m1 - M);
            size_t r = (size_t)(rb * BM + tid);
            Pm[r * 256 + cb] = M;
            Ps[r * 256 + cb] = S;
        }
    }
}

template<int BM, int BN, int MODE>
static void launch_gemm(const bf16* A, const bf16* B, float* C, int M, int N, int K,
                        int lda, int ldb, int ldc, float* Pm, float* Ps, hipStream_t stream)
{
    int RB = M / BM;
    int CB = (N + BN - 1) / BN;
    int CBpad = (CB + 7) & ~7;
    gemm_bt<BM, BN, MODE><<<RB * CBpad, 256, 0, stream>>>(A, B, C, K, lda, ldb, ldc, Pm, Ps, RB, CB, CBpad);
}

// ---------------- fused conv+SiLU+x_proj ----------------
// block: 4 tokens, 256 threads, grid NTOK/4 = 256.
// computes u = silu(conv(xz_u) + cb) in LDS from xz, writes u_bf (bf16),
// x_dbl = u @ xw^T (f = tid&127 < 96, 2-way k-split), writes xdbl f32 + dt bf16.
__global__ __launch_bounds__(256) void cxk_kernel(
        const float* __restrict__ xz, const float* __restrict__ cw,
        const float* __restrict__ cb, const float* __restrict__ xw,
        float* __restrict__ xdbl, bf16* __restrict__ dt_bf, bf16* __restrict__ u_bf)
{
    int t0  = blockIdx.x * 4;
    int bb  = t0 >> 9;                 // batch index
    int tid = threadIdx.x;
    int f   = tid & 127;
    int ks  = tid >> 7;                // k-split half
    __shared__ __align__(16) float sxz[7][256];
    __shared__ __align__(16) float su[4][256];
    __shared__ float pacc[4][128];
    float acc[4] = {0, 0, 0, 0};
    for (int kc = 0; kc < DI_DIM; kc += 256) {
        __syncthreads();
        // load xz rows t0-3 .. t0+3, cols kc..kc+255 (zero outside batch)
#pragma unroll
        for (int i = 0; i < 2; ++i) {
            int idx = i * 256 + tid;          // 0..511, need < 448
            if (idx < 448) {
                int row = idx >> 6, c4 = (idx & 63) * 4;
                int tr = t0 - 3 + row;
                f32x4 v = {0, 0, 0, 0};
                if (tr >= bb * L_SEQ)
                    v = *(const f32x4*)&xz[(size_t)tr * (2 * DI_DIM) + kc + c4];
                *(f32x4*)&sxz[row][c4] = v;
            }
        }
        __syncthreads();
        // conv + silu: one col per thread
        {
            int c = tid;
            const float* cwp = cw + (size_t)(kc + c) * DC_DIM;
            float w0 = cwp[0], w1 = cwp[1], w2 = cwp[2], w3 = cwp[3];
            float bs = cb[kc + c];
#pragma unroll
            for (int tt = 0; tt < 4; ++tt) {
                float a = bs + w0 * sxz[tt][c] + w1 * sxz[tt + 1][c]
                             + w2 * sxz[tt + 2][c] + w3 * sxz[tt + 3][c];
                float uo = a / (1.0f + __expf(-a));
                su[tt][c] = uo;
                u_bf[(size_t)(t0 + tt) * DI_DIM + kc + c] = (bf16)uo;
            }
        }
        __syncthreads();
        // x_proj partial accumulate (k-split halves)
        if (f < 96) {
            int kb = ks * 128;
            for (int kk = kb; kk < kb + 128; kk += 4) {
                f32x4 wv = *(const f32x4*)&xw[(size_t)f * DI_DIM + kc + kk];
#pragma unroll
                for (int tt = 0; tt < 4; ++tt) {
                    f32x4 uv = *(f32x4*)&su[tt][kk];
                    acc[tt] += wv[0]*uv[0] + wv[1]*uv[1] + wv[2]*uv[2] + wv[3]*uv[3];
                }
            }
        }
    }
    // merge k-split halves and write
    if (ks == 1 && f < 96) {
#pragma unroll
        for (int tt = 0; tt < 4; ++tt) pacc[tt][f] = acc[tt];
    }
    __syncthreads();
    if (ks == 0 && f < 96) {
#pragma unroll
        for (int tt = 0; tt < 4; ++tt) {
            float v = acc[tt] + pacc[tt][f];
            xdbl[(size_t)(t0 + tt) * 96 + f] = v;
            if (f < 64) dt_bf[(size_t)(t0 + tt) * DTR_DIM + f] = (bf16)v;
        }
    }
}

// ---------------- chunked selective scan (delta computed on the fly) ----------------
// delta[t][d] = softplus(dt[t,:64] . dtw[d,:64] + dtb[d]) recomputed identically in both phases.
__global__ __launch_bounds__(256) void scan_phase_a(
        const bf16* __restrict__ dt_g, const float* __restrict__ dtw,
        const float* __restrict__ dtb, const float* __restrict__ xdbl,
        const bf16* __restrict__ u_bf, const float* __restrict__ A_log,
        float* __restrict__ Pbuf, float* __restrict__ Sbuf)
{
    int tid = threadIdx.x;
    int c   = blockIdx.x & (NC - 1);
    int dblk= (blockIdx.x >> 3) & 127;
    int b   = blockIdx.x >> 10;
    int d0  = dblk << 4;
    int n = tid & 15, dl = tid >> 4;
    int d = d0 + dl;
    float Ac = -expf(A_log[(size_t)d * NS_DIM + n]);
    float h = 0.0f, P = 1.0f;
    __shared__ float s_dt[32][65];
    __shared__ float s_dtw[16][64];
    __shared__ float s_dtb[16];
    __shared__ float s_dlt[32][17];
    __shared__ float s_u[32][16], s_B[32][16];
    {   // stage dtw/dtb once
        int idx = tid * 4;
        int rowD = idx >> 6, c4 = idx & 63;
        *(f32x4*)&s_dtw[rowD][c4] = *(const f32x4*)&dtw[(size_t)(d0 + rowD) * DTR_DIM + c4];
        if (tid < 16) s_dtb[tid] = dtb[d0 + tid];
    }
    int tt0 = tid >> 4, cc = tid & 15;
    int tbase = b * L_SEQ + c * LC;
    for (int t0 = 0; t0 < LC; t0 += 32) {
        __syncthreads();
        {   // stage dt rows (bf16 -> f32)
            int row = tid >> 3, c8 = (tid & 7) * 8;
            bf16x8 v = *(const bf16x8*)&dt_g[(size_t)(tbase + t0 + row) * DTR_DIM + c8];
#pragma unroll
            for (int jj = 0; jj < 8; ++jj) s_dt[row][c8 + jj] = (float)v[jj];
        }
#pragma unroll
        for (int jj = 0; jj < 2; ++jj) {
            int tt = jj * 16 + tt0;
            size_t trow = (size_t)(tbase + t0 + tt);
            s_u[tt][cc] = (float)u_bf[trow * DI_DIM + d0 + cc];
            s_B[tt][cc] = xdbl[trow * 96 + 64 + cc];
        }
        __syncthreads();
        {   // delta tile: 32 t x 16 d, two d per thread
            int td = tid & 31, dd = tid >> 5;
            float a0 = s_dtb[dd], a1 = s_dtb[dd + 8];
#pragma unroll
            for (int k = 0; k < 64; ++k) {
                float a = s_dt[td][k];
                a0 = fmaf(a, s_dtw[dd][k], a0);
                a1 = fmaf(a, s_dtw[dd + 8][k], a1);
            }
            s_dlt[td][dd]     = softplusf(a0);
            s_dlt[td][dd + 8] = softplusf(a1);
        }
        __syncthreads();
#pragma unroll
        for (int t = 0; t < 32; ++t) {
            float dlt = s_dlt[t][dl];
            float dA  = __expf(dlt * Ac);
            h = fmaf(dA, h, dlt * s_B[t][n] * s_u[t][dl]);
            P *= dA;
        }
    }
    size_t oi = (((size_t)(b * NC + c) * DI_DIM) + d) * NS_DIM + n;
    Pbuf[oi] = P;
    Sbuf[oi] = h;
}

__global__ void scan_combine(const float* __restrict__ Pbuf, const float* __restrict__ Sbuf,
                             float* __restrict__ Hstart)
{
    int i  = blockIdx.x * 256 + threadIdx.x;
    int b  = i >> 15;
    int dn = i & 32767;
    float h = 0.0f;
#pragma unroll
    for (int c = 0; c < NC; ++c) {
        size_t oi = ((size_t)(b * NC + c) * (DI_DIM * NS_DIM)) + dn;
        Hstart[oi] = h;
        h = fmaf(Pbuf[oi], h, Sbuf[oi]);
    }
}

__global__ __launch_bounds__(256) void scan_phase_c(
        const bf16* __restrict__ dt_g, const float* __restrict__ dtw,
        const float* __restrict__ dtb, const float* __restrict__ xdbl,
        const bf16* __restrict__ u_bf, const float* __restrict__ xz,
        const float* __restrict__ A_log, const float* __restrict__ D_par,
        const float* __restrict__ Hstart, bf16* __restrict__ y)
{
    int tid = threadIdx.x;
    int c   = blockIdx.x & (NC - 1);
    int dblk= (blockIdx.x >> 3) & 127;
    int b   = blockIdx.x >> 10;
    int d0  = dblk << 4;
    int n = tid & 15, dl = tid >> 4;
    int d = d0 + dl;
    float Ac = -expf(A_log[(size_t)d * NS_DIM + n]);
    float Dp = D_par[d];
    float h = Hstart[(((size_t)(b * NC + c) * DI_DIM) + d) * NS_DIM + n];
    __shared__ float s_dt[32][65];
    __shared__ float s_dtw[16][64];
    __shared__ float s_dtb[16];
    __shared__ float s_dlt[32][17];
    __shared__ float s_u[32][16], s_res[32][16], s_B[32][16], s_C[32][16];
    __shared__ bf16  s_y[32][16];
    {
        int idx = tid * 4;
        int rowD = idx >> 6, c4 = idx & 63;
        *(f32x4*)&s_dtw[rowD][c4] = *(const f32x4*)&dtw[(size_t)(d0 + rowD) * DTR_DIM + c4];
        if (tid < 16) s_dtb[tid] = dtb[d0 + tid];
    }
    int tt0 = tid >> 4, cc = tid & 15;
    int tbase = b * L_SEQ + c * LC;
    for (int t0 = 0; t0 < LC; t0 += 32) {
        __syncthreads();
        {
            int row = tid >> 3, c8 = (tid & 7) * 8;
            bf16x8 v = *(const bf16x8*)&dt_g[(size_t)(tbase + t0 + row) * DTR_DIM + c8];
#pragma unroll
            for (int jj = 0; jj < 8; ++jj) s_dt[row][c8 + jj] = (float)v[jj];
        }
#pragma unroll
        for (int jj = 0; jj < 2; ++jj) {
            int tt = jj * 16 + tt0;
            size_t trow = (size_t)(tbase + t0 + tt);
            s_u[tt][cc]   = (float)u_bf[trow * DI_DIM + d0 + cc];
            s_res[tt][cc] = xz[trow * (2 * DI_DIM) + DI_DIM + d0 + cc];
            s_B[tt][cc]   = xdbl[trow * 96 + 64 + cc];
            s_C[tt][cc]   = xdbl[trow * 96 + 80 + cc];
        }
        __syncthreads();
        {
            int td = tid & 31, dd = tid >> 5;
            float a0 = s_dtb[dd], a1 = s_dtb[dd + 8];
#pragma unroll
            for (int k = 0; k < 64; ++k) {
                float a = s_dt[td][k];
                a0 = fmaf(a, s_dtw[dd][k], a0);
                a1 = fmaf(a, s_dtw[dd + 8][k], a1);
            }
            s_dlt[td][dd]     = softplusf(a0);
            s_dlt[td][dd + 8] = softplusf(a1);
        }
        __syncthreads();
#pragma unroll
        for (int t = 0; t < 32; ++t) {
            float dlt = s_dlt[t][dl];
            float uu  = s_u[t][dl];
            float dA  = __expf(dlt * Ac);
            float dBu = dlt * s_B[t][n] * uu;
            h = fmaf(dA, h, dBu);
            float yp = h * s_C[t][n];
            yp += __shfl_xor(yp, 1);
            yp += __shfl_xor(yp, 2);
            yp += __shfl_xor(yp, 4);
            yp += __shfl_xor(yp, 8);
            if (n == 0) {
                float res = s_res[t][dl];
                float yv  = fmaf(uu, Dp, yp) * (res / (1.0f + __expf(-res)));
                s_y[t][dl] = (bf16)yv;
            }
        }
        __syncthreads();
#pragma unroll
        for (int jj = 0; jj < 2; ++jj) {
            int tt = jj * 16 + tt0;
            size_t trow = (size_t)(tbase + t0 + tt);
            y[trow * DI_DIM + d0 + cc] = s_y[tt][cc];
        }
    }
}

// ---------------- lse finalize from per-colblock partials + NLL ----------------
__global__ void lse_fin_kernel(const float* __restrict__ Pm, const float* __restrict__ Ps,
                               const float* __restrict__ logits, const int* __restrict__ targets,
                               float* __restrict__ nll)
{
    int t = blockIdx.x, tid = threadIdx.x;
    float m = -1e30f, s = 0.0f;
    for (int i = tid; i < CB_LOG; i += 256) {
        float mo = Pm[(size_t)t * 256 + i], so = Ps[(size_t)t * 256 + i];
        float nm = fmaxf(m, mo);
        s = s * __expf(m - nm) + so * __expf(mo - nm);
        m = nm;
    }
#pragma unroll
    for (int off = 1; off < 64; off <<= 1) {
        float mo = __shfl_xor(m, off), so = __shfl_xor(s, off);
        float nm = fmaxf(m, mo);
        s = s * __expf(m - nm) + so * __expf(mo - nm);
        m = nm;
    }
    __shared__ float pm[4], ps2[4];
    if ((tid & 63) == 0) { pm[tid >> 6] = m; ps2[tid >> 6] = s; }
    __syncthreads();
    if (tid == 0) {
        float M = fmaxf(fmaxf(pm[0], pm[1]), fmaxf(pm[2], pm[3]));
        float S = ps2[0] * __expf(pm[0] - M) + ps2[1] * __expf(pm[1] - M)
                + ps2[2] * __expf(pm[2] - M) + ps2[3] * __expf(pm[3] - M);
        int tg = targets[t];
        float v = 0.0f;
        if (tg >= 0) v = (M + logf(S)) - logits[(size_t)t * V_DIM + tg];
        nll[t] = v;
    }
}

__global__ void loss_reduce_kernel(const float* __restrict__ nll, float* __restrict__ out)
{
    int tid = threadIdx.x;
    float s = 0.0f;
    for (int i = tid; i < NTOK; i += 256) s += nll[i];
#pragma unroll
    for (int off = 1; off < 64; off <<= 1) s += __shfl_xor(s, off);
    __shared__ float p[4];
    if ((tid & 63) == 0) p[tid >> 6] = s;
    __syncthreads();
    if (tid == 0) out[0] = (p[0] + p[1] + p[2] + p[3]) * (1.0f / NTOK);
}

// ---------------- host launcher ----------------
extern "C" void kernel_launch(void* const* d_in, const int* in_sizes, int n_in,
                              void* d_out, int out_size, void* d_ws, size_t ws_size,
                              hipStream_t stream)
{
    const int*   ids   = (const int*)d_in[0];
    const int*   tgt   = (const int*)d_in[1];
    const float* emb   = (const float*)d_in[2];
    const float* ln_w  = (const float*)d_in[3];
    const float* ln_b  = (const float*)d_in[4];
    const float* inw   = (const float*)d_in[5];
    const float* convw = (const float*)d_in[6];
    const float* convb = (const float*)d_in[7];
    const float* xw    = (const float*)d_in[8];
    const float* dtw   = (const float*)d_in[9];
    const float* dtb   = (const float*)d_in[10];
    const float* alog  = (const float*)d_in[11];
    const float* dpar  = (const float*)d_in[12];
    const float* outw  = (const float*)d_in[13];
    const float* flnw  = (const float*)d_in[14];
    const float* flnb  = (const float*)d_in[15];
    float* logits = (float*)d_out;
    float* lossp  = logits + (size_t)NTOK * V_DIM;

    char* wsp = (char*)d_ws;
    size_t off = 0;
    auto alloc = [&](size_t bytes) -> void* {
        void* p = wsp + off;
        off += (bytes + 255) & ~(size_t)255;
        return p;
    };
    bf16*  emb_bf  = (bf16*)alloc((size_t)V_DIM * E_DIM * 2);           // 65.5 MB
    bf16*  winl    = (bf16*)alloc((size_t)2 * DI_DIM * E_DIM * 2);      // 8.4 MB (per-layer)
    bf16*  woutl   = (bf16*)alloc((size_t)E_DIM * DI_DIM * 2);          // 4.2 MB
    float* x       = (float*)alloc((size_t)NTOK * E_DIM * 4);
    bf16*  h_bf    = (bf16*)alloc((size_t)NTOK * E_DIM * 2);
    float* xzb     = (float*)alloc((size_t)NTOK * 2 * DI_DIM * 4);      // 16 MB
    bf16*  u_bf    = (bf16*)alloc((size_t)NTOK * DI_DIM * 2);           // 4 MB
    float* xdbl    = (float*)alloc((size_t)NTOK * 96 * 4);
    bf16*  dt_bf   = (bf16*)alloc((size_t)NTOK * DTR_DIM * 2);
    bf16*  y_bf    = (bf16*)alloc((size_t)NTOK * DI_DIM * 2);
    bf16*  xf_bf   = (bf16*)alloc((size_t)NTOK * E_DIM * 2);
    float* nll     = (float*)alloc((size_t)NTOK * 4);
    float* Pbuf    = (float*)alloc((size_t)NBATCH * NC * DI_DIM * NS_DIM * 4);
    float* Sbuf    = (float*)alloc((size_t)NBATCH * NC * DI_DIM * NS_DIM * 4);
    float* Hstart  = (float*)alloc((size_t)NBATCH * NC * DI_DIM * NS_DIM * 4);
    float* Pm      = (float*)alloc((size_t)NTOK * 256 * 4);             // 1 MB
    float* Ps      = (float*)alloc((size_t)NTOK * 256 * 4);             // 1 MB
    if (off > ws_size) return;

    {   // emb cast
        int n4 = (int)((size_t)V_DIM * E_DIM / 4);
        cast_f32_to_bf16<<<4096, 256, 0, stream>>>(emb, emb_bf, n4);
    }
    embed_kernel<<<NTOK, 256, 0, stream>>>(ids, emb, x);

    for (int l = 0; l < NL_DIM; ++l) {
        cast2_kernel<<<2048, 256, 0, stream>>>(
            inw  + (size_t)l * 2 * DI_DIM * E_DIM, winl,  (int)((size_t)2 * DI_DIM * E_DIM / 4),
            outw + (size_t)l * E_DIM * DI_DIM,     woutl, (int)((size_t)E_DIM * DI_DIM / 4));

        ln_kernel<<<NTOK, 256, 0, stream>>>(x, ln_w + l * E_DIM, ln_b + l * E_DIM, h_bf);
        // xz[1024,4096] = h @ in_w^T
        launch_gemm<128, 64, 0>(h_bf, winl, xzb, NTOK, 2 * DI_DIM, E_DIM,
                                E_DIM, E_DIM, 2 * DI_DIM, nullptr, nullptr, stream);
        // fused conv+silu+x_proj
        cxk_kernel<<<NTOK / 4, 256, 0, stream>>>(
            xzb, convw + (size_t)l * DI_DIM * DC_DIM, convb + (size_t)l * DI_DIM,
            xw + (size_t)l * 96 * DI_DIM, xdbl, dt_bf, u_bf);
        // chunked scan (delta on the fly)
        scan_phase_a<<<NBATCH * (DI_DIM / 16) * NC, 256, 0, stream>>>(
            dt_bf, dtw + (size_t)l * DI_DIM * DTR_DIM, dtb + (size_t)l * DI_DIM,
            xdbl, u_bf, alog + (size_t)l * DI_DIM * NS_DIM, Pbuf, Sbuf);
        scan_combine<<<NBATCH * DI_DIM * NS_DIM / 256, 256, 0, stream>>>(Pbuf, Sbuf, Hstart);
        scan_phase_c<<<NBATCH * (DI_DIM / 16) * NC, 256, 0, stream>>>(
            dt_bf, dtw + (size_t)l * DI_DIM * DTR_DIM, dtb + (size_t)l * DI_DIM,
            xdbl, u_bf, xzb, alog + (size_t)l * DI_DIM * NS_DIM, dpar + (size_t)l * DI_DIM,
            Hstart, y_bf);
        // x += y @ out_w^T
        launch_gemm<64, 64, 1>(y_bf, woutl, x, NTOK, E_DIM, DI_DIM,
                               DI_DIM, DI_DIM, E_DIM, nullptr, nullptr, stream);
    }
    ln_kernel<<<NTOK, 256, 0, stream>>>(x, flnw, flnb, xf_bf);
    // logits = x_f @ emb^T  (+ per-row lse partials)
    launch_gemm<128, 128, 3>(xf_bf, emb_bf, logits, NTOK, V_DIM, E_DIM,
                             E_DIM, E_DIM, V_DIM, Pm, Ps, stream);
    lse_fin_kernel<<<NTOK, 256, 0, stream>>>(Pm, Ps, logits, tgt, nll);
    loss_reduce_kernel<<<1, 256, 0, stream>>>(nll, lossp);
}

// Round 6
// 884.947 us; speedup vs baseline: 1.8137x; 1.0395x over previous
//
#include <hip/hip_runtime.h>
#include <cstdint>
#include <cstddef>

#define L_SEQ 512
#define NBATCH 2
#define NTOK 1024          // B*L
#define E_DIM 1024
#define V_DIM 32000
#define DI_DIM 2048
#define NS_DIM 16
#define DTR_DIM 64
#define DC_DIM 4
#define NL_DIM 4
#define NC 8               // time chunks for parallel scan
#define LC (L_SEQ / NC)    // 64
#define CB_LOG 250         // logits col-blocks (32000/128)

typedef __bf16 bf16;
typedef __bf16 bf16x8 __attribute__((ext_vector_type(8)));
typedef __bf16 bf16x4 __attribute__((ext_vector_type(4)));
typedef float  f32x4  __attribute__((ext_vector_type(4)));

// async global->LDS, 16B per lane. LDS dest must be wave-uniform base (+lane*16 implicit).
__device__ __forceinline__ void gload_lds16(const void* g, void* l)
{
    __builtin_amdgcn_global_load_lds((const __attribute__((address_space(1))) uint32_t*)g,
                                     (__attribute__((address_space(3))) uint32_t*)l, 16, 0, 0);
}

__device__ __forceinline__ float softplusf(float z)
{
    return fmaxf(z, 0.0f) + log1pf(expf(-fabsf(z)));
}

// ---------------- cast f32 -> bf16 (grid-stride, x4) ----------------
__global__ void cast_f32_to_bf16(const float* __restrict__ in, bf16* __restrict__ out, int n4)
{
    int stride = gridDim.x * blockDim.x;
    for (int i = blockIdx.x * blockDim.x + threadIdx.x; i < n4; i += stride) {
        f32x4 v = ((const f32x4*)in)[i];
        bf16x4 o;
        o[0] = (bf16)v[0]; o[1] = (bf16)v[1]; o[2] = (bf16)v[2]; o[3] = (bf16)v[3];
        ((bf16x4*)out)[i] = o;
    }
}

// fused 3-tensor cast (per layer: in_w, out_w, dt_w)
__global__ void cast3_kernel(const float* __restrict__ a, bf16* __restrict__ oa, int na4,
                             const float* __restrict__ b, bf16* __restrict__ ob, int nb4,
                             const float* __restrict__ c, bf16* __restrict__ oc, int nc4)
{
    int stride = gridDim.x * blockDim.x;
    int tot = na4 + nb4 + nc4;
    for (int i = blockIdx.x * blockDim.x + threadIdx.x; i < tot; i += stride) {
        const float* src; bf16* dst; int k = i;
        if (k < na4) { src = a; dst = oa; }
        else if ((k -= na4) < nb4) { src = b; dst = ob; }
        else { k -= nb4; src = c; dst = oc; }
        f32x4 v = ((const f32x4*)src)[k];
        bf16x4 o;
        o[0] = (bf16)v[0]; o[1] = (bf16)v[1]; o[2] = (bf16)v[2]; o[3] = (bf16)v[3];
        ((bf16x4*)dst)[k] = o;
    }
}

// ---------------- embedding gather ----------------
__global__ void embed_kernel(const int* __restrict__ ids, const float* __restrict__ emb,
                             float* __restrict__ x)
{
    int t = blockIdx.x;
    int id = ids[t];
    ((f32x4*)(x + (size_t)t * E_DIM))[threadIdx.x] =
        ((const f32x4*)(emb + (size_t)id * E_DIM))[threadIdx.x];
}

// ---------------- LayerNorm (row=1024), bf16 out ----------------
__global__ void ln_kernel(const float* __restrict__ x, const float* __restrict__ w,
                          const float* __restrict__ b, bf16* __restrict__ out)
{
    int t = blockIdx.x;
    int tid = threadIdx.x;
    f32x4 v = ((const f32x4*)(x + (size_t)t * E_DIM))[tid];
    float s  = v[0] + v[1] + v[2] + v[3];
    float sq = v[0]*v[0] + v[1]*v[1] + v[2]*v[2] + v[3]*v[3];
#pragma unroll
    for (int off = 1; off < 64; off <<= 1) { s += __shfl_xor(s, off); sq += __shfl_xor(sq, off); }
    __shared__ float ps[4], pq[4];
    if ((tid & 63) == 0) { ps[tid >> 6] = s; pq[tid >> 6] = sq; }
    __syncthreads();
    float S  = ps[0] + ps[1] + ps[2] + ps[3];
    float SQ = pq[0] + pq[1] + pq[2] + pq[3];
    float mu  = S * (1.0f / E_DIM);
    float var = SQ * (1.0f / E_DIM) - mu * mu;
    float rs  = rsqrtf(var + 1e-5f);
    f32x4 wv = ((const f32x4*)w)[tid];
    f32x4 bv = ((const f32x4*)b)[tid];
    bf16x4 o;
#pragma unroll
    for (int i = 0; i < 4; ++i) o[i] = (bf16)((v[i] - mu) * rs * wv[i] + bv[i]);
    ((bf16x4*)(out + (size_t)t * E_DIM))[tid] = o;
}

// ---------------- MFMA bf16 GEMM: C[M,N] = A[M,K] * B[N,K]^T ----------------
// Tiles BM x BN, BK=32, 256 threads (4 waves 2x2). global_load_lds staging.
// 1-D grid, XCD-chunked col swizzle.
// MODE 0: f32 store; MODE 1: f32 C += (residual);
// MODE 2: bf16 C = softplus(acc + bias[col]);
// MODE 3: f32 store + slim per-row (max,sumexp) partials -> Pm/Ps[row*512 + cb*2 + wc];
// MODE 4: bf16 store.
template<int BM, int BN, int MODE>
__global__ __launch_bounds__(256) void gemm_bt(const bf16* __restrict__ A, const bf16* __restrict__ B,
                                               void* __restrict__ Cv, int K,
                                               int lda, int ldb, int ldc,
                                               const float* __restrict__ bias,
                                               float* __restrict__ Pm, float* __restrict__ Ps,
                                               int RB, int CB, int CBpad)
{
    int pid = blockIdx.x;
    int xcd = pid & 7;
    int j   = pid >> 3;
    int cpx = CBpad >> 3;
    int rb  = j % RB;
    int cb  = xcd * cpx + j / RB;
    if (cb >= CB) return;

    __shared__ __align__(16) bf16 As[BM * 32];
    __shared__ __align__(16) bf16 Bs[BN * 32];
    int tid  = threadIdx.x;
    int lane = tid & 63;
    int wid  = tid >> 6;
    int wr = wid >> 1, wc = wid & 1;
    int li = lane & 15, lg = lane >> 4;
    const bf16* Ablk = A + (size_t)(rb * BM) * lda;
    const bf16* Bblk = B + (size_t)(cb * BN) * ldb;
    constexpr int MR  = BM / 32;
    constexpr int NR  = BN / 32;
    constexpr int TOT = (BM + BN) * 4;    // 16B lane-ops per K-step
    f32x4 acc[MR][NR] = {};
    for (int k0 = 0; k0 < K; k0 += 32) {
        __syncthreads();
#pragma unroll
        for (int it = 0; it < TOT / 256; ++it) {
            int wbase = it * 256 + wid * 64;
            int idx   = wbase + lane;
            if (wbase < BM * 4) {
                int row = idx >> 2, seg = idx & 3;
                gload_lds16(Ablk + (size_t)row * lda + k0 + seg * 8, As + (size_t)wbase * 8);
            } else {
                int bb  = wbase - BM * 4;
                int bi  = bb + lane;
                int row = bi >> 2, seg = bi & 3;
                gload_lds16(Bblk + (size_t)row * ldb + k0 + seg * 8, Bs + (size_t)bb * 8);
            }
        }
        __syncthreads();
        bf16x8 af[MR], bfr[NR];
#pragma unroll
        for (int m = 0; m < MR; ++m) af[m]  = *(const bf16x8*)&As[(wr * (BM/2) + m * 16 + li) * 32 + lg * 8];
#pragma unroll
        for (int n = 0; n < NR; ++n) bfr[n] = *(const bf16x8*)&Bs[(wc * (BN/2) + n * 16 + li) * 32 + lg * 8];
#pragma unroll
        for (int m = 0; m < MR; ++m)
#pragma unroll
            for (int n = 0; n < NR; ++n)
                acc[m][n] = __builtin_amdgcn_mfma_f32_16x16x32_bf16(af[m], bfr[n], acc[m][n], 0, 0, 0);
    }
    int row0 = rb * BM + wr * (BM/2);
    int col0 = cb * BN + wc * (BN/2);
    float* Cf = (float*)Cv;
    bf16*  Cb = (bf16*)Cv;
#pragma unroll
    for (int m = 0; m < MR; ++m) {
#pragma unroll
        for (int n = 0; n < NR; ++n) {
            int r = row0 + m * 16 + lg * 4;
            int c = col0 + n * 16 + li;
#pragma unroll
            for (int q = 0; q < 4; ++q) {
                float v = acc[m][n][q];
                if (MODE == 0 || MODE == 3) {
                    Cf[(size_t)(r + q) * ldc + c] = v;
                } else if (MODE == 1) {
                    float* cp = Cf + (size_t)(r + q) * ldc + c;
                    *cp = v + *cp;
                } else if (MODE == 2) {
                    Cb[(size_t)(r + q) * ldc + c] = (bf16)softplusf(v + bias[c]);
                } else if (MODE == 4) {
                    Cb[(size_t)(r + q) * ldc + c] = (bf16)v;
                }
            }
        }
    }
    if constexpr (MODE == 3) {
        // slim LSE partials: each half-wave owns rows row0..row0+63, cols col0..col0+63.
        // shfl offsets <16 only mix li (lane&15) -> reduce across the 16 cols each lane group holds.
#pragma unroll
        for (int m = 0; m < MR; ++m) {
#pragma unroll
            for (int q = 0; q < 4; ++q) {
                float mx = acc[m][0][q];
#pragma unroll
                for (int n = 1; n < NR; ++n) mx = fmaxf(mx, acc[m][n][q]);
#pragma unroll
                for (int off = 1; off < 16; off <<= 1) mx = fmaxf(mx, __shfl_xor(mx, off));
                float sv = 0.0f;
#pragma unroll
                for (int n = 0; n < NR; ++n) sv += __expf(acc[m][n][q] - mx);
#pragma unroll
                for (int off = 1; off < 16; off <<= 1) sv += __shfl_xor(sv, off);
                if (li == 0) {
                    size_t r = (size_t)(row0 + m * 16 + lg * 4 + q);
                    Pm[r * 512 + cb * 2 + wc] = mx;
                    Ps[r * 512 + cb * 2 + wc] = sv;
                }
            }
        }
    }
}

template<int BM, int BN, int MODE>
static void launch_gemm(const bf16* A, const bf16* B, void* C, int M, int N, int K,
                        int lda, int ldb, int ldc, const float* bias,
                        float* Pm, float* Ps, hipStream_t stream)
{
    int RB = M / BM;
    int CB = (N + BN - 1) / BN;
    int CBpad = (CB + 7) & ~7;
    gemm_bt<BM, BN, MODE><<<RB * CBpad, 256, 0, stream>>>(A, B, C, K, lda, ldb, ldc,
                                                          bias, Pm, Ps, RB, CB, CBpad);
}

// ---------------- fused conv+SiLU+x_proj (xz bf16 in) ----------------
// block: 4 tokens, 256 threads, grid NTOK/4 = 256.
__global__ __launch_bounds__(256) void cxk_kernel(
        const bf16* __restrict__ xz, const float* __restrict__ cw,
        const float* __restrict__ cb, const float* __restrict__ xw,
        float* __restrict__ xdbl, bf16* __restrict__ dt_bf, bf16* __restrict__ u_bf)
{
    int t0  = blockIdx.x * 4;
    int bb  = t0 >> 9;                 // batch index
    int tid = threadIdx.x;
    int f   = tid & 127;
    int ks  = tid >> 7;                // k-split half
    __shared__ __align__(16) float sxz[7][256];
    __shared__ __align__(16) float su[4][256];
    __shared__ float pacc[4][128];
    float acc[4] = {0, 0, 0, 0};
    for (int kc = 0; kc < DI_DIM; kc += 256) {
        __syncthreads();
        // load xz rows t0-3 .. t0+3, cols kc..kc+255 (bf16 -> f32, zero outside batch)
        if (tid < 224) {
            int row = tid >> 5, c8 = (tid & 31) * 8;
            int tr = t0 - 3 + row;
            float vals[8] = {0, 0, 0, 0, 0, 0, 0, 0};
            if (tr >= bb * L_SEQ) {
                bf16x8 v = *(const bf16x8*)&xz[(size_t)tr * (2 * DI_DIM) + kc + c8];
#pragma unroll
                for (int jj = 0; jj < 8; ++jj) vals[jj] = (float)v[jj];
            }
#pragma unroll
            for (int jj = 0; jj < 8; ++jj) sxz[row][c8 + jj] = vals[jj];
        }
        __syncthreads();
        // conv + silu: one col per thread
        {
            int c = tid;
            const float* cwp = cw + (size_t)(kc + c) * DC_DIM;
            float w0 = cwp[0], w1 = cwp[1], w2 = cwp[2], w3 = cwp[3];
            float bs = cb[kc + c];
#pragma unroll
            for (int tt = 0; tt < 4; ++tt) {
                float a = bs + w0 * sxz[tt][c] + w1 * sxz[tt + 1][c]
                             + w2 * sxz[tt + 2][c] + w3 * sxz[tt + 3][c];
                float uo = a / (1.0f + __expf(-a));
                su[tt][c] = uo;
                u_bf[(size_t)(t0 + tt) * DI_DIM + kc + c] = (bf16)uo;
            }
        }
        __syncthreads();
        // x_proj partial accumulate (k-split halves)
        if (f < 96) {
            int kb = ks * 128;
            for (int kk = kb; kk < kb + 128; kk += 4) {
                f32x4 wv = *(const f32x4*)&xw[(size_t)f * DI_DIM + kc + kk];
#pragma unroll
                for (int tt = 0; tt < 4; ++tt) {
                    f32x4 uv = *(f32x4*)&su[tt][kk];
                    acc[tt] += wv[0]*uv[0] + wv[1]*uv[1] + wv[2]*uv[2] + wv[3]*uv[3];
                }
            }
        }
    }
    // merge k-split halves and write
    if (ks == 1 && f < 96) {
#pragma unroll
        for (int tt = 0; tt < 4; ++tt) pacc[tt][f] = acc[tt];
    }
    __syncthreads();
    if (ks == 0 && f < 96) {
#pragma unroll
        for (int tt = 0; tt < 4; ++tt) {
            float v = acc[tt] + pacc[tt][f];
            xdbl[(size_t)(t0 + tt) * 96 + f] = v;
            if (f < 64) dt_bf[(size_t)(t0 + tt) * DTR_DIM + f] = (bf16)v;
        }
    }
}

// ---------------- chunked selective scan (delta precomputed, bf16) ----------------
__global__ __launch_bounds__(256) void scan_phase_a(
        const bf16* __restrict__ delta, const float* __restrict__ xdbl,
        const bf16* __restrict__ u_bf, const float* __restrict__ A_log,
        float* __restrict__ Pbuf, float* __restrict__ Sbuf)
{
    int tid = threadIdx.x;
    int c   = blockIdx.x & (NC - 1);
    int dblk= (blockIdx.x >> 3) & 127;
    int b   = blockIdx.x >> 10;
    int d0  = dblk << 4;
    int n = tid & 15, dl = tid >> 4;
    int d = d0 + dl;
    float Ac = -expf(A_log[(size_t)d * NS_DIM + n]);
    float h = 0.0f, P = 1.0f;
    __shared__ float s_dlt[32][16], s_u[32][16], s_B[32][16];
    int tt0 = tid >> 4, cc = tid & 15;
    int tbase = b * L_SEQ + c * LC;
    for (int t0 = 0; t0 < LC; t0 += 32) {
        __syncthreads();
#pragma unroll
        for (int jj = 0; jj < 2; ++jj) {
            int tt = jj * 16 + tt0;
            size_t trow = (size_t)(tbase + t0 + tt);
            s_dlt[tt][cc] = (float)delta[trow * DI_DIM + d0 + cc];
            s_u[tt][cc]   = (float)u_bf[trow * DI_DIM + d0 + cc];
            s_B[tt][cc]   = xdbl[trow * 96 + 64 + cc];
        }
        __syncthreads();
#pragma unroll
        for (int t = 0; t < 32; ++t) {
            float dlt = s_dlt[t][dl];
            float dA  = __expf(dlt * Ac);
            h = fmaf(dA, h, dlt * s_B[t][n] * s_u[t][dl]);
            P *= dA;
        }
    }
    size_t oi = (((size_t)(b * NC + c) * DI_DIM) + d) * NS_DIM + n;
    Pbuf[oi] = P;
    Sbuf[oi] = h;
}

__global__ void scan_combine(const float* __restrict__ Pbuf, const float* __restrict__ Sbuf,
                             float* __restrict__ Hstart)
{
    int i  = blockIdx.x * 256 + threadIdx.x;
    int b  = i >> 15;
    int dn = i & 32767;
    float h = 0.0f;
#pragma unroll
    for (int c = 0; c < NC; ++c) {
        size_t oi = ((size_t)(b * NC + c) * (DI_DIM * NS_DIM)) + dn;
        Hstart[oi] = h;
        h = fmaf(Pbuf[oi], h, Sbuf[oi]);
    }
}

__global__ __launch_bounds__(256) void scan_phase_c(
        const bf16* __restrict__ delta, const float* __restrict__ xdbl,
        const bf16* __restrict__ u_bf, const bf16* __restrict__ xz,
        const float* __restrict__ A_log, const float* __restrict__ D_par,
        const float* __restrict__ Hstart, bf16* __restrict__ y)
{
    int tid = threadIdx.x;
    int c   = blockIdx.x & (NC - 1);
    int dblk= (blockIdx.x >> 3) & 127;
    int b   = blockIdx.x >> 10;
    int d0  = dblk << 4;
    int n = tid & 15, dl = tid >> 4;
    int d = d0 + dl;
    float Ac = -expf(A_log[(size_t)d * NS_DIM + n]);
    float Dp = D_par[d];
    float h = Hstart[(((size_t)(b * NC + c) * DI_DIM) + d) * NS_DIM + n];
    __shared__ float s_dlt[32][16], s_u[32][16], s_res[32][16], s_B[32][16], s_C[32][16];
    __shared__ bf16  s_y[32][16];
    int tt0 = tid >> 4, cc = tid & 15;
    int tbase = b * L_SEQ + c * LC;
    for (int t0 = 0; t0 < LC; t0 += 32) {
        __syncthreads();
#pragma unroll
        for (int jj = 0; jj < 2; ++jj) {
            int tt = jj * 16 + tt0;
            size_t trow = (size_t)(tbase + t0 + tt);
            s_dlt[tt][cc] = (float)delta[trow * DI_DIM + d0 + cc];
            s_u[tt][cc]   = (float)u_bf[trow * DI_DIM + d0 + cc];
            s_res[tt][cc] = (float)xz[trow * (2 * DI_DIM) + DI_DIM + d0 + cc];
            s_B[tt][cc]   = xdbl[trow * 96 + 64 + cc];
            s_C[tt][cc]   = xdbl[trow * 96 + 80 + cc];
        }
        __syncthreads();
#pragma unroll
        for (int t = 0; t < 32; ++t) {
            float dlt = s_dlt[t][dl];
            float uu  = s_u[t][dl];
            float dA  = __expf(dlt * Ac);
            float dBu = dlt * s_B[t][n] * uu;
            h = fmaf(dA, h, dBu);
            float yp = h * s_C[t][n];
            yp += __shfl_xor(yp, 1);
            yp += __shfl_xor(yp, 2);
            yp += __shfl_xor(yp, 4);
            yp += __shfl_xor(yp, 8);
            if (n == 0) {
                float res = s_res[t][dl];
                float yv  = fmaf(uu, Dp, yp) * (res / (1.0f + __expf(-res)));
                s_y[t][dl] = (bf16)yv;
            }
        }
        __syncthreads();
#pragma unroll
        for (int jj = 0; jj < 2; ++jj) {
            int tt = jj * 16 + tt0;
            size_t trow = (size_t)(tbase + t0 + tt);
            y[trow * DI_DIM + d0 + cc] = s_y[tt][cc];
        }
    }
}

// ---------------- lse finalize from per-halfblock partials + NLL + loss atomic ----------------
__global__ void lse_fin_kernel(const float* __restrict__ Pm, const float* __restrict__ Ps,
                               const float* __restrict__ logits, const int* __restrict__ targets,
                               float* __restrict__ lossp)
{
    int t = blockIdx.x, tid = threadIdx.x;
    float m = -1e30f, s = 0.0f;
    for (int i = tid; i < 2 * CB_LOG; i += 256) {
        float mo = Pm[(size_t)t * 512 + i], so = Ps[(size_t)t * 512 + i];
        float nm = fmaxf(m, mo);
        s = s * __expf(m - nm) + so * __expf(mo - nm);
        m = nm;
    }
#pragma unroll
    for (int off = 1; off < 64; off <<= 1) {
        float mo = __shfl_xor(m, off), so = __shfl_xor(s, off);
        float nm = fmaxf(m, mo);
        s = s * __expf(m - nm) + so * __expf(mo - nm);
        m = nm;
    }
    __shared__ float pm[4], ps2[4];
    if ((tid & 63) == 0) { pm[tid >> 6] = m; ps2[tid >> 6] = s; }
    __syncthreads();
    if (tid == 0) {
        float M = fmaxf(fmaxf(pm[0], pm[1]), fmaxf(pm[2], pm[3]));
        float S = ps2[0] * __expf(pm[0] - M) + ps2[1] * __expf(pm[1] - M)
                + ps2[2] * __expf(pm[2] - M) + ps2[3] * __expf(pm[3] - M);
        int tg = targets[t];
        if (tg >= 0) {
            float v = (M + logf(S)) - logits[(size_t)t * V_DIM + tg];
            atomicAdd(lossp, v * (1.0f / NTOK));
        }
    }
}

// ---------------- host launcher ----------------
extern "C" void kernel_launch(void* const* d_in, const int* in_sizes, int n_in,
                              void* d_out, int out_size, void* d_ws, size_t ws_size,
                              hipStream_t stream)
{
    const int*   ids   = (const int*)d_in[0];
    const int*   tgt   = (const int*)d_in[1];
    const float* emb   = (const float*)d_in[2];
    const float* ln_w  = (const float*)d_in[3];
    const float* ln_b  = (const float*)d_in[4];
    const float* inw   = (const float*)d_in[5];
    const float* convw = (const float*)d_in[6];
    const float* convb = (const float*)d_in[7];
    const float* xw    = (const float*)d_in[8];
    const float* dtw   = (const float*)d_in[9];
    const float* dtb   = (const float*)d_in[10];
    const float* alog  = (const float*)d_in[11];
    const float* dpar  = (const float*)d_in[12];
    const float* outw  = (const float*)d_in[13];
    const float* flnw  = (const float*)d_in[14];
    const float* flnb  = (const float*)d_in[15];
    float* logits = (float*)d_out;
    float* lossp  = logits + (size_t)NTOK * V_DIM;

    char* wsp = (char*)d_ws;
    size_t off = 0;
    auto alloc = [&](size_t bytes) -> void* {
        void* p = wsp + off;
        off += (bytes + 255) & ~(size_t)255;
        return p;
    };
    bf16*  emb_bf  = (bf16*)alloc((size_t)V_DIM * E_DIM * 2);           // 65.5 MB
    bf16*  winl    = (bf16*)alloc((size_t)2 * DI_DIM * E_DIM * 2);      // 8.4 MB (per-layer)
    bf16*  woutl   = (bf16*)alloc((size_t)E_DIM * DI_DIM * 2);          // 4.2 MB
    bf16*  wdtl    = (bf16*)alloc((size_t)DI_DIM * DTR_DIM * 2);        // 0.26 MB
    float* x       = (float*)alloc((size_t)NTOK * E_DIM * 4);
    bf16*  h_bf    = (bf16*)alloc((size_t)NTOK * E_DIM * 2);
    bf16*  xzb     = (bf16*)alloc((size_t)NTOK * 2 * DI_DIM * 2);       // 8.4 MB
    bf16*  u_bf    = (bf16*)alloc((size_t)NTOK * DI_DIM * 2);           // 4.2 MB
    float* xdbl    = (float*)alloc((size_t)NTOK * 96 * 4);
    bf16*  dt_bf   = (bf16*)alloc((size_t)NTOK * DTR_DIM * 2);
    bf16*  deltab  = (bf16*)alloc((size_t)NTOK * DI_DIM * 2);           // 4.2 MB
    bf16*  y_bf    = (bf16*)alloc((size_t)NTOK * DI_DIM * 2);
    bf16*  xf_bf   = (bf16*)alloc((size_t)NTOK * E_DIM * 2);
    float* Pbuf    = (float*)alloc((size_t)NBATCH * NC * DI_DIM * NS_DIM * 4);
    float* Sbuf    = (float*)alloc((size_t)NBATCH * NC * DI_DIM * NS_DIM * 4);
    float* Hstart  = (float*)alloc((size_t)NBATCH * NC * DI_DIM * NS_DIM * 4);
    float* Pm      = (float*)alloc((size_t)NTOK * 512 * 4);             // 2.1 MB
    float* Ps      = (float*)alloc((size_t)NTOK * 512 * 4);             // 2.1 MB
    if (off > ws_size) return;

    hipMemsetAsync(lossp, 0, sizeof(float), stream);
    {   // emb cast
        int n4 = (int)((size_t)V_DIM * E_DIM / 4);
        cast_f32_to_bf16<<<4096, 256, 0, stream>>>(emb, emb_bf, n4);
    }
    embed_kernel<<<NTOK, 256, 0, stream>>>(ids, emb, x);

    for (int l = 0; l < NL_DIM; ++l) {
        cast3_kernel<<<2048, 256, 0, stream>>>(
            inw  + (size_t)l * 2 * DI_DIM * E_DIM, winl,  (int)((size_t)2 * DI_DIM * E_DIM / 4),
            outw + (size_t)l * E_DIM * DI_DIM,     woutl, (int)((size_t)E_DIM * DI_DIM / 4),
            dtw  + (size_t)l * DI_DIM * DTR_DIM,   wdtl,  (int)((size_t)DI_DIM * DTR_DIM / 4));

        ln_kernel<<<NTOK, 256, 0, stream>>>(x, ln_w + l * E_DIM, ln_b + l * E_DIM, h_bf);
        // xz[1024,4096] = h @ in_w^T  (bf16 out)
        launch_gemm<128, 64, 4>(h_bf, winl, xzb, NTOK, 2 * DI_DIM, E_DIM,
                                E_DIM, E_DIM, 2 * DI_DIM, nullptr, nullptr, nullptr, stream);
        // fused conv+silu+x_proj
        cxk_kernel<<<NTOK / 4, 256, 0, stream>>>(
            xzb, convw + (size_t)l * DI_DIM * DC_DIM, convb + (size_t)l * DI_DIM,
            xw + (size_t)l * 96 * DI_DIM, xdbl, dt_bf, u_bf);
        // delta[1024,2048] = softplus(dt @ dtw^T + dtb) (bf16 out)
        launch_gemm<64, 64, 2>(dt_bf, wdtl, deltab, NTOK, DI_DIM, DTR_DIM,
                               DTR_DIM, DTR_DIM, DI_DIM, dtb + (size_t)l * DI_DIM,
                               nullptr, nullptr, stream);
        // chunked scan
        scan_phase_a<<<NBATCH * (DI_DIM / 16) * NC, 256, 0, stream>>>(
            deltab, xdbl, u_bf, alog + (size_t)l * DI_DIM * NS_DIM, Pbuf, Sbuf);
        scan_combine<<<NBATCH * DI_DIM * NS_DIM / 256, 256, 0, stream>>>(Pbuf, Sbuf, Hstart);
        scan_phase_c<<<NBATCH * (DI_DIM / 16) * NC, 256, 0, stream>>>(
            deltab, xdbl, u_bf, xzb, alog + (size_t)l * DI_DIM * NS_DIM,
            dpar + (size_t)l * DI_DIM, Hstart, y_bf);
        // x += y @ out_w^T
        launch_gemm<64, 64, 1>(y_bf, woutl, x, NTOK, E_DIM, DI_DIM,
                               DI_DIM, DI_DIM, E_DIM, nullptr, nullptr, nullptr, stream);
    }
    ln_kernel<<<NTOK, 256, 0, stream>>>(x, flnw, flnb, xf_bf);
    // logits = x_f @ emb^T  (+ slim per-row lse partials)
    launch_gemm<128, 128, 3>(xf_bf, emb_bf, logits, NTOK, V_DIM, E_DIM,
                             E_DIM, E_DIM, V_DIM, nullptr, Pm, Ps, stream);
    lse_fin_kernel<<<NTOK, 256, 0, stream>>>(Pm, Ps, logits, tgt, lossp);
}